// Round 1
// baseline (7666.691 us; speedup 1.0000x reference)
//
#include <hip/hip_runtime.h>
#include <hip/hip_bf16.h>
#include <math.h>

#define T_TOK 2048
#define H_DIM 2048
#define E_NUM 64
#define F_DIM 512
#define K_TOP 8
#define FS_DIM 512

// ---------------------------------------------------------------------------
// Router: one wave per token. Lane l accumulates logit for expert l (l<64);
// col 64 (shared gate) reduced across lanes. Top-8 by iterated wave-argmax,
// weights = softmax over the top-8 logits (== renormalized softmax probs).
// ---------------------------------------------------------------------------
__global__ __launch_bounds__(64) void router_kernel(
    const float* __restrict__ x, const float* __restrict__ Wg,
    int* __restrict__ topk_idx, float* __restrict__ topk_w,
    float* __restrict__ sgate, int* __restrict__ counts)
{
    const int t = blockIdx.x;
    const int lane = threadIdx.x;
    const float* xr = x + (size_t)t * H_DIM;

    float a0 = 0.f, a1 = 0.f, a2 = 0.f, a3 = 0.f;
    for (int h = 0; h < H_DIM; h += 4) {
        float4 xv = *(const float4*)&xr[h];
        a0 += xv.x * Wg[(h + 0) * 65 + lane];
        a1 += xv.y * Wg[(h + 1) * 65 + lane];
        a2 += xv.z * Wg[(h + 2) * 65 + lane];
        a3 += xv.w * Wg[(h + 3) * 65 + lane];
    }
    float logit = (a0 + a1) + (a2 + a3);

    // shared-gate logit (column 64), parallel partial + butterfly reduce
    float a64 = 0.f;
    for (int h = lane; h < H_DIM; h += 64) a64 += xr[h] * Wg[h * 65 + 64];
#pragma unroll
    for (int off = 32; off >= 1; off >>= 1) a64 += __shfl_xor(a64, off);

    // top-8 via 8 iterated wave argmax reductions
    float v = logit;
    float selv[K_TOP]; int seli[K_TOP];
#pragma unroll
    for (int k = 0; k < K_TOP; ++k) {
        float mv = v; int mi = lane;
#pragma unroll
        for (int off = 32; off >= 1; off >>= 1) {
            float ov = __shfl_xor(mv, off);
            int   oi = __shfl_xor(mi, off);
            if (ov > mv || (ov == mv && oi < mi)) { mv = ov; mi = oi; }
        }
        selv[k] = mv; seli[k] = mi;
        if (lane == mi) v = -INFINITY;
    }

    if (lane == 0) {
        float m = selv[0];
        float w[K_TOP]; float s = 0.f;
#pragma unroll
        for (int k = 0; k < K_TOP; ++k) { w[k] = expf(selv[k] - m); s += w[k]; }
        float inv = 1.f / s;
#pragma unroll
        for (int k = 0; k < K_TOP; ++k) {
            topk_idx[t * K_TOP + k] = seli[k];
            topk_w[t * K_TOP + k] = w[k] * inv;
            atomicAdd(&counts[seli[k]], 1);
        }
        sgate[t] = 1.f / (1.f + expf(-a64));
    }
}

// ---------------------------------------------------------------------------
// Deterministic bucket build: block e scans all T*K assignments in token
// order, compacts matching (token, weight) pairs to offsets[e]..  Order is
// fully deterministic (counts are int-atomic sums; ranks by entry index).
// ---------------------------------------------------------------------------
__global__ __launch_bounds__(256) void bucket_kernel(
    const int* __restrict__ topk_idx, const float* __restrict__ topk_w,
    const int* __restrict__ counts, int* __restrict__ offsets,
    int* __restrict__ bucket_tok, float* __restrict__ bucket_w)
{
    const int e = blockIdx.x, thr = threadIdx.x;
    __shared__ int cnt[256];
    __shared__ int base_s;
    const int q0 = thr * 64;
    int c = 0;
    for (int q = 0; q < 64; ++q) c += (topk_idx[q0 + q] == e) ? 1 : 0;
    cnt[thr] = c;
    __syncthreads();
    if (thr == 0) {
        int off = 0;
        for (int i = 0; i < e; ++i) off += counts[i];
        offsets[e] = off;
        base_s = off;
        int run = 0;
        for (int i = 0; i < 256; ++i) { int tval = cnt[i]; cnt[i] = run; run += tval; }
    }
    __syncthreads();
    int pos = base_s + cnt[thr];
    for (int q = 0; q < 64; ++q) {
        int pp = q0 + q;
        if (topk_idx[pp] == e) {
            bucket_tok[pos] = pp >> 3;     // token id
            bucket_w[pos] = topk_w[pp];
            ++pos;
        }
    }
}

// ---------------------------------------------------------------------------
// Routed gate_up + SiLU*u*topw. Block: 64 bucket rows x 128 act cols
// (needs g cols [c0,c0+128) and u cols [512+c0, 512+c0+128) of W_gate_up[e]).
// 256 thr = 8(ty) x 32(tx); 8x8 register tile per thread; cols split as
// {g: tx*4+j, u: 128+tx*4+j} in LDS so each thread owns matching g/u pairs.
// ---------------------------------------------------------------------------
__global__ __launch_bounds__(256) void moe_guact_kernel(
    const float* __restrict__ x, const float* __restrict__ Wgu,
    const int* __restrict__ counts, const int* __restrict__ offsets,
    const int* __restrict__ bucket_tok, const float* __restrict__ bucket_w,
    float* __restrict__ act)
{
    const int tt = blockIdx.x, ft = blockIdx.y, e = blockIdx.z;
    const int ne = counts[e];
    if (tt * 64 >= ne) return;
    const int base = offsets[e];
    const int c0 = ft * 128;

    __shared__ __align__(16) float XgT[32][68];
    __shared__ __align__(16) float Wt[32][260];
    __shared__ int   toks[64];
    __shared__ float tws[64];

    const int thr = threadIdx.x;
    const int ty = thr >> 5, tx = thr & 31;

    if (thr < 64) {
        int idx = tt * 64 + thr;
        bool valid = idx < ne;
        toks[thr] = valid ? bucket_tok[base + idx] : 0;
        tws[thr]  = valid ? bucket_w[base + idx] : 0.f;
    }

    float acc[8][8];
#pragma unroll
    for (int i = 0; i < 8; ++i)
#pragma unroll
        for (int j = 0; j < 8; ++j) acc[i][j] = 0.f;

    __syncthreads();

    const float* We = Wgu + (size_t)e * H_DIM * (2 * F_DIM);

    for (int k0 = 0; k0 < H_DIM; k0 += 32) {
        // stage gathered X^T tile: 64 rows x 32 k  -> XgT[k][row]
#pragma unroll
        for (int j = 0; j < 8; ++j) {
            int q = thr + 256 * j;
            int row = q >> 5, kk = q & 31;
            XgT[kk][row] = x[(size_t)toks[row] * H_DIM + k0 + kk];
        }
        // stage W tile: 32 k x (128 g | 128 u)
#pragma unroll
        for (int j = 0; j < 8; ++j) {
            int q = thr + 256 * j;
            int row = q >> 6, f4 = q & 63;
            int gc = (f4 < 32) ? (c0 + f4 * 4) : (512 + c0 + (f4 - 32) * 4);
            float4 wv = *(const float4*)&We[(size_t)(k0 + row) * (2 * F_DIM) + gc];
            *(float4*)&Wt[row][f4 * 4] = wv;
        }
        __syncthreads();
#pragma unroll 4
        for (int kk = 0; kk < 32; ++kk) {
            float a[8], b[8];
            *(float4*)&a[0] = *(const float4*)&XgT[kk][ty * 8];
            *(float4*)&a[4] = *(const float4*)&XgT[kk][ty * 8 + 4];
            *(float4*)&b[0] = *(const float4*)&Wt[kk][tx * 4];
            *(float4*)&b[4] = *(const float4*)&Wt[kk][128 + tx * 4];
#pragma unroll
            for (int i = 0; i < 8; ++i)
#pragma unroll
                for (int jj = 0; jj < 8; ++jj)
                    acc[i][jj] += a[i] * b[jj];
        }
        __syncthreads();
    }

#pragma unroll
    for (int i = 0; i < 8; ++i) {
        int idx = tt * 64 + ty * 8 + i;
        if (idx < ne) {
            float w = tws[ty * 8 + i];
            float o[4];
#pragma unroll
            for (int jj = 0; jj < 4; ++jj) {
                float g = acc[i][jj], u = acc[i][4 + jj];
                float s = g / (1.f + expf(-g));
                o[jj] = s * u * w;
            }
            *(float4*)&act[(size_t)(base + idx) * F_DIM + c0 + tx * 4] = *(float4*)o;
        }
    }
}

// ---------------------------------------------------------------------------
// Routed down-proj: act(packed) @ W_down[e] -> atomicAdd into out rows.
// Block: 64 bucket rows x 256 out cols.
// ---------------------------------------------------------------------------
__global__ __launch_bounds__(256) void moe_down_kernel(
    const float* __restrict__ act, const float* __restrict__ Wd,
    const int* __restrict__ counts, const int* __restrict__ offsets,
    const int* __restrict__ bucket_tok,
    float* __restrict__ out)
{
    const int tt = blockIdx.x, ct = blockIdx.y, e = blockIdx.z;
    const int ne = counts[e];
    if (tt * 64 >= ne) return;
    const int base = offsets[e];
    const int c0 = ct * 256;

    __shared__ __align__(16) float AT[32][68];
    __shared__ __align__(16) float Wt[32][260];
    __shared__ int toks[64];

    const int thr = threadIdx.x;
    const int ty = thr >> 5, tx = thr & 31;

    if (thr < 64) {
        int idx = tt * 64 + thr;
        toks[thr] = (idx < ne) ? bucket_tok[base + idx] : 0;
    }

    float acc[8][8];
#pragma unroll
    for (int i = 0; i < 8; ++i)
#pragma unroll
        for (int j = 0; j < 8; ++j) acc[i][j] = 0.f;

    __syncthreads();

    const float* We = Wd + (size_t)e * F_DIM * H_DIM;

    for (int k0 = 0; k0 < F_DIM; k0 += 32) {
#pragma unroll
        for (int j = 0; j < 8; ++j) {
            int q = thr + 256 * j;
            int row = q >> 5, kk = q & 31;
            int idx = tt * 64 + row;
            int gp = base + ((idx < ne) ? idx : 0);
            AT[kk][row] = act[(size_t)gp * F_DIM + k0 + kk];
        }
#pragma unroll
        for (int j = 0; j < 8; ++j) {
            int q = thr + 256 * j;
            int row = q >> 6, f4 = q & 63;
            float4 wv = *(const float4*)&We[(size_t)(k0 + row) * H_DIM + c0 + f4 * 4];
            *(float4*)&Wt[row][f4 * 4] = wv;
        }
        __syncthreads();
#pragma unroll 4
        for (int kk = 0; kk < 32; ++kk) {
            float a[8], b[8];
            *(float4*)&a[0] = *(const float4*)&AT[kk][ty * 8];
            *(float4*)&a[4] = *(const float4*)&AT[kk][ty * 8 + 4];
            *(float4*)&b[0] = *(const float4*)&Wt[kk][tx * 4];
            *(float4*)&b[4] = *(const float4*)&Wt[kk][128 + tx * 4];
#pragma unroll
            for (int i = 0; i < 8; ++i)
#pragma unroll
                for (int jj = 0; jj < 8; ++jj)
                    acc[i][jj] += a[i] * b[jj];
        }
        __syncthreads();
    }

#pragma unroll
    for (int i = 0; i < 8; ++i) {
        int idx = tt * 64 + ty * 8 + i;
        if (idx < ne) {
            int tok = toks[ty * 8 + i];
            float* orow = out + (size_t)tok * H_DIM + c0;
#pragma unroll
            for (int jj = 0; jj < 4; ++jj) atomicAdd(&orow[tx * 4 + jj], acc[i][jj]);
#pragma unroll
            for (int jj = 0; jj < 4; ++jj) atomicAdd(&orow[128 + tx * 4 + jj], acc[i][4 + jj]);
        }
    }
}

// ---------------------------------------------------------------------------
// Shared expert gate_up + SiLU*u (all tokens, no gather/weight)
// ---------------------------------------------------------------------------
__global__ __launch_bounds__(256) void shared_guact_kernel(
    const float* __restrict__ x, const float* __restrict__ Wgu,
    float* __restrict__ act)
{
    const int tt = blockIdx.x, ft = blockIdx.y;
    const int c0 = ft * 128;

    __shared__ __align__(16) float XgT[32][68];
    __shared__ __align__(16) float Wt[32][260];

    const int thr = threadIdx.x;
    const int ty = thr >> 5, tx = thr & 31;

    float acc[8][8];
#pragma unroll
    for (int i = 0; i < 8; ++i)
#pragma unroll
        for (int j = 0; j < 8; ++j) acc[i][j] = 0.f;

    __syncthreads();

    for (int k0 = 0; k0 < H_DIM; k0 += 32) {
#pragma unroll
        for (int j = 0; j < 8; ++j) {
            int q = thr + 256 * j;
            int row = q >> 5, kk = q & 31;
            XgT[kk][row] = x[(size_t)(tt * 64 + row) * H_DIM + k0 + kk];
        }
#pragma unroll
        for (int j = 0; j < 8; ++j) {
            int q = thr + 256 * j;
            int row = q >> 6, f4 = q & 63;
            int gc = (f4 < 32) ? (c0 + f4 * 4) : (512 + c0 + (f4 - 32) * 4);
            float4 wv = *(const float4*)&Wgu[(size_t)(k0 + row) * (2 * FS_DIM) + gc];
            *(float4*)&Wt[row][f4 * 4] = wv;
        }
        __syncthreads();
#pragma unroll 4
        for (int kk = 0; kk < 32; ++kk) {
            float a[8], b[8];
            *(float4*)&a[0] = *(const float4*)&XgT[kk][ty * 8];
            *(float4*)&a[4] = *(const float4*)&XgT[kk][ty * 8 + 4];
            *(float4*)&b[0] = *(const float4*)&Wt[kk][tx * 4];
            *(float4*)&b[4] = *(const float4*)&Wt[kk][128 + tx * 4];
#pragma unroll
            for (int i = 0; i < 8; ++i)
#pragma unroll
                for (int jj = 0; jj < 8; ++jj)
                    acc[i][jj] += a[i] * b[jj];
        }
        __syncthreads();
    }

#pragma unroll
    for (int i = 0; i < 8; ++i) {
        int t = tt * 64 + ty * 8 + i;
        float o[4];
#pragma unroll
        for (int jj = 0; jj < 4; ++jj) {
            float g = acc[i][jj], u = acc[i][4 + jj];
            float s = g / (1.f + expf(-g));
            o[jj] = s * u;
        }
        *(float4*)&act[(size_t)t * FS_DIM + c0 + tx * 4] = *(float4*)o;
    }
}

// ---------------------------------------------------------------------------
// Shared expert down-proj: act_s @ Ws_down, scaled by sigmoid(gate), WRITES out
// (runs before routed down kernel which atomically accumulates on top).
// ---------------------------------------------------------------------------
__global__ __launch_bounds__(256) void shared_down_kernel(
    const float* __restrict__ act, const float* __restrict__ Wd,
    const float* __restrict__ sgate, float* __restrict__ out)
{
    const int tt = blockIdx.x, ct = blockIdx.y;
    const int c0 = ct * 256;

    __shared__ __align__(16) float AT[32][68];
    __shared__ __align__(16) float Wt[32][260];
    __shared__ float sgs[64];

    const int thr = threadIdx.x;
    const int ty = thr >> 5, tx = thr & 31;

    if (thr < 64) sgs[thr] = sgate[tt * 64 + thr];

    float acc[8][8];
#pragma unroll
    for (int i = 0; i < 8; ++i)
#pragma unroll
        for (int j = 0; j < 8; ++j) acc[i][j] = 0.f;

    __syncthreads();

    for (int k0 = 0; k0 < FS_DIM; k0 += 32) {
#pragma unroll
        for (int j = 0; j < 8; ++j) {
            int q = thr + 256 * j;
            int row = q >> 5, kk = q & 31;
            AT[kk][row] = act[(size_t)(tt * 64 + row) * FS_DIM + k0 + kk];
        }
#pragma unroll
        for (int j = 0; j < 8; ++j) {
            int q = thr + 256 * j;
            int row = q >> 6, f4 = q & 63;
            float4 wv = *(const float4*)&Wd[(size_t)(k0 + row) * H_DIM + c0 + f4 * 4];
            *(float4*)&Wt[row][f4 * 4] = wv;
        }
        __syncthreads();
#pragma unroll 4
        for (int kk = 0; kk < 32; ++kk) {
            float a[8], b[8];
            *(float4*)&a[0] = *(const float4*)&AT[kk][ty * 8];
            *(float4*)&a[4] = *(const float4*)&AT[kk][ty * 8 + 4];
            *(float4*)&b[0] = *(const float4*)&Wt[kk][tx * 4];
            *(float4*)&b[4] = *(const float4*)&Wt[kk][128 + tx * 4];
#pragma unroll
            for (int i = 0; i < 8; ++i)
#pragma unroll
                for (int jj = 0; jj < 8; ++jj)
                    acc[i][jj] += a[i] * b[jj];
        }
        __syncthreads();
    }

#pragma unroll
    for (int i = 0; i < 8; ++i) {
        int t = tt * 64 + ty * 8 + i;
        float sg = sgs[ty * 8 + i];
        float* orow = out + (size_t)t * H_DIM + c0;
        float o[4];
#pragma unroll
        for (int jj = 0; jj < 4; ++jj) o[jj] = sg * acc[i][jj];
        *(float4*)&orow[tx * 4] = *(float4*)o;
#pragma unroll
        for (int jj = 0; jj < 4; ++jj) o[jj] = sg * acc[i][4 + jj];
        *(float4*)&orow[128 + tx * 4] = *(float4*)o;
    }
}

// ---------------------------------------------------------------------------
extern "C" void kernel_launch(void* const* d_in, const int* in_sizes, int n_in,
                              void* d_out, int out_size, void* d_ws, size_t ws_size,
                              hipStream_t stream) {
    const float* x    = (const float*)d_in[0];
    const float* Wg   = (const float*)d_in[1];
    const float* Wgu  = (const float*)d_in[2];
    const float* Wd   = (const float*)d_in[3];
    const float* Wsgu = (const float*)d_in[4];
    const float* Wsd  = (const float*)d_in[5];
    float* out = (float*)d_out;

    char* p = (char*)d_ws;
    auto alloc = [&](size_t bytes) {
        char* r = p;
        p += (bytes + 255) & ~(size_t)255;
        return r;
    };
    int*   topk_idx   = (int*)  alloc((size_t)T_TOK * K_TOP * sizeof(int));
    float* topk_w     = (float*)alloc((size_t)T_TOK * K_TOP * sizeof(float));
    float* sgate      = (float*)alloc((size_t)T_TOK * sizeof(float));
    int*   counts     = (int*)  alloc((size_t)E_NUM * sizeof(int));
    int*   offsets    = (int*)  alloc((size_t)E_NUM * sizeof(int));
    int*   bucket_tok = (int*)  alloc((size_t)T_TOK * K_TOP * sizeof(int));
    float* bucket_w   = (float*)alloc((size_t)T_TOK * K_TOP * sizeof(float));
    float* act_r      = (float*)alloc((size_t)T_TOK * K_TOP * F_DIM * sizeof(float));
    float* act_s      = (float*)alloc((size_t)T_TOK * FS_DIM * sizeof(float));

    hipMemsetAsync(counts, 0, E_NUM * sizeof(int), stream);
    router_kernel<<<T_TOK, 64, 0, stream>>>(x, Wg, topk_idx, topk_w, sgate, counts);
    bucket_kernel<<<E_NUM, 256, 0, stream>>>(topk_idx, topk_w, counts, offsets, bucket_tok, bucket_w);
    moe_guact_kernel<<<dim3(32, 4, E_NUM), 256, 0, stream>>>(x, Wgu, counts, offsets, bucket_tok, bucket_w, act_r);
    shared_guact_kernel<<<dim3(32, 4), 256, 0, stream>>>(x, Wsgu, act_s);
    shared_down_kernel<<<dim3(32, 8), 256, 0, stream>>>(act_s, Wsd, sgate, out);
    moe_down_kernel<<<dim3(32, 8, E_NUM), 256, 0, stream>>>(act_r, Wd, counts, offsets, bucket_tok, out);
}

// Round 2
// 1003.956 us; speedup vs baseline: 7.6365x; 7.6365x over previous
//
#include <hip/hip_runtime.h>
#include <hip/hip_bf16.h>
#include <math.h>

#define T_TOK 2048
#define H_DIM 2048
#define E_NUM 64
#define F_DIM 512
#define K_TOP 8
#define FS_DIM 512
#define NROWS (T_TOK * K_TOP)

typedef __attribute__((ext_vector_type(8))) short short8v;   // bf16x8 MFMA frag
typedef __attribute__((ext_vector_type(4))) float f32x4;     // MFMA accum

static __device__ __forceinline__ unsigned short f2bf(float f) {
    unsigned int u = __float_as_uint(f);
    u += 0x7fff + ((u >> 16) & 1);           // RNE to bf16
    return (unsigned short)(u >> 16);
}

// ---------------------------------------------------------------------------
// x (fp32) -> bf16 copy, vectorized 8/thread
// ---------------------------------------------------------------------------
__global__ __launch_bounds__(256) void cvt_bf16_kernel(
    const float* __restrict__ in, unsigned short* __restrict__ out, int n8)
{
    int i = blockIdx.x * 256 + threadIdx.x;
    if (i < n8) {
        const float4* p = (const float4*)(in + (size_t)i * 8);
        float4 v0 = p[0], v1 = p[1];
        ushort4 a = make_ushort4(f2bf(v0.x), f2bf(v0.y), f2bf(v0.z), f2bf(v0.w));
        ushort4 b = make_ushort4(f2bf(v1.x), f2bf(v1.y), f2bf(v1.z), f2bf(v1.w));
        ushort4* q = (ushort4*)(out + (size_t)i * 8);
        q[0] = a; q[1] = b;
    }
}

// ---------------------------------------------------------------------------
// Router: one wave per token (fp32 x for exact top-k selection).
// ---------------------------------------------------------------------------
__global__ __launch_bounds__(64) void router_kernel(
    const float* __restrict__ x, const float* __restrict__ Wg,
    int* __restrict__ topk_idx, float* __restrict__ topk_w,
    float* __restrict__ sgate, int* __restrict__ counts)
{
    const int t = blockIdx.x;
    const int lane = threadIdx.x;
    const float* xr = x + (size_t)t * H_DIM;

    float a0 = 0.f, a1 = 0.f, a2 = 0.f, a3 = 0.f;
    for (int h = 0; h < H_DIM; h += 4) {
        float4 xv = *(const float4*)&xr[h];
        a0 += xv.x * Wg[(h + 0) * 65 + lane];
        a1 += xv.y * Wg[(h + 1) * 65 + lane];
        a2 += xv.z * Wg[(h + 2) * 65 + lane];
        a3 += xv.w * Wg[(h + 3) * 65 + lane];
    }
    float logit = (a0 + a1) + (a2 + a3);

    float a64 = 0.f;
    for (int h = lane; h < H_DIM; h += 64) a64 += xr[h] * Wg[h * 65 + 64];
#pragma unroll
    for (int off = 32; off >= 1; off >>= 1) a64 += __shfl_xor(a64, off);

    float v = logit;
    float selv[K_TOP]; int seli[K_TOP];
#pragma unroll
    for (int k = 0; k < K_TOP; ++k) {
        float mv = v; int mi = lane;
#pragma unroll
        for (int off = 32; off >= 1; off >>= 1) {
            float ov = __shfl_xor(mv, off);
            int   oi = __shfl_xor(mi, off);
            if (ov > mv || (ov == mv && oi < mi)) { mv = ov; mi = oi; }
        }
        selv[k] = mv; seli[k] = mi;
        if (lane == mi) v = -INFINITY;
    }

    if (lane == 0) {
        float m = selv[0];
        float w[K_TOP]; float s = 0.f;
#pragma unroll
        for (int k = 0; k < K_TOP; ++k) { w[k] = __expf(selv[k] - m); s += w[k]; }
        float inv = 1.f / s;
#pragma unroll
        for (int k = 0; k < K_TOP; ++k) {
            topk_idx[t * K_TOP + k] = seli[k];
            topk_w[t * K_TOP + k] = w[k] * inv;
            atomicAdd(&counts[seli[k]], 1);
        }
        sgate[t] = 1.f / (1.f + __expf(-a64));
    }
}

// ---------------------------------------------------------------------------
// Deterministic per-expert compaction.
// ---------------------------------------------------------------------------
__global__ __launch_bounds__(256) void bucket_kernel(
    const int* __restrict__ topk_idx, const float* __restrict__ topk_w,
    const int* __restrict__ counts, int* __restrict__ offsets,
    int* __restrict__ bucket_tok, float* __restrict__ bucket_w)
{
    const int e = blockIdx.x, thr = threadIdx.x;
    __shared__ int cnt[256];
    __shared__ int base_s;
    const int q0 = thr * 64;
    int c = 0;
    for (int q = 0; q < 64; ++q) c += (topk_idx[q0 + q] == e) ? 1 : 0;
    cnt[thr] = c;
    __syncthreads();
    if (thr == 0) {
        int off = 0;
        for (int i = 0; i < e; ++i) off += counts[i];
        offsets[e] = off;
        base_s = off;
        int run = 0;
        for (int i = 0; i < 256; ++i) { int tval = cnt[i]; cnt[i] = run; run += tval; }
    }
    __syncthreads();
    int pos = base_s + cnt[thr];
    for (int q = 0; q < 64; ++q) {
        int pp = q0 + q;
        if (topk_idx[pp] == e) {
            bucket_tok[pos] = pp >> 3;
            bucket_w[pos] = topk_w[pp];
            ++pos;
        }
    }
}

// ---------------------------------------------------------------------------
// MFMA grouped gate_up + SiLU*u*(topw). BM=256 rows x 64 act cols (128 W cols:
// [g c0..c0+31 | u c0..c0+31 | g c0+32..63 | u c0+32..63]).
// 512 thr = 8 waves (4 wm x 2 wn), wave = 64 rows x 32 act cols, 4x4 16x16 frags.
// LDS: A[256][64] bf16, B(W^T)[128][64] bf16, both XOR-swizzled in 16B chunks.
// ---------------------------------------------------------------------------
template<bool ROUTED>
__global__ __launch_bounds__(512, 1) void gu_mfma_kernel(
    const unsigned short* __restrict__ xb,
    const float* __restrict__ Wall,
    const int* __restrict__ counts, const int* __restrict__ offsets,
    const int* __restrict__ bucket_tok, const float* __restrict__ bucket_w,
    unsigned short* __restrict__ actout)
{
    __shared__ __align__(16) unsigned short As[256 * 64];
    __shared__ __align__(16) unsigned short Bs[128 * 64];
    __shared__ int   toksS[256];
    __shared__ float twsS[256];

    const int tid  = threadIdx.x;
    const int lane = tid & 63;
    const int wid  = tid >> 6;
    const int wm = wid >> 1, wn = wid & 1;
    const int lrow = lane & 15, lhi = lane >> 4;

    const int c0 = blockIdx.x * 64;    // act-col base == W g-col base
    int ne, base, m0_init, m_end;
    const float* W;
    if (ROUTED) {
        int e = blockIdx.y;
        ne = counts[e]; base = offsets[e];
        m0_init = 0; m_end = ne;
        W = Wall + (size_t)e * H_DIM * (2 * F_DIM);
    } else {
        ne = T_TOK; base = 0;
        m0_init = blockIdx.y * 256; m_end = m0_init + 256;
        W = Wall;
    }

    // B staging unit: 4 cols x 4 k-rows per thread
    const int c4  = (tid & 31) * 4;    // LDS W^T row base (0..124)
    const int k4  = tid >> 5;          // 0..15, k-row base = k4*4
    const int sub = c4 >> 5;           // 0..3 -> {g0,u0,g1,u1}
    const int srcc = c0 + ((sub >> 1) << 5) + (c4 & 31) + (sub & 1) * F_DIM;

    for (int m0 = m0_init; m0 < m_end; m0 += 256) {
        __syncthreads();
        if (tid < 256) {
            if (ROUTED) {
                int idx = m0 + tid; bool v = idx < ne;
                toksS[tid] = v ? bucket_tok[base + idx] : bucket_tok[base];
                twsS[tid]  = v ? bucket_w[base + idx] : 0.f;
            } else {
                toksS[tid] = m0 + tid; twsS[tid] = 1.f;
            }
        }
        __syncthreads();

        f32x4 acc[4][4];
#pragma unroll
        for (int i = 0; i < 4; ++i)
#pragma unroll
            for (int j = 0; j < 4; ++j) acc[i][j] = (f32x4){0.f, 0.f, 0.f, 0.f};

        uint4  areg[4];
        float4 breg[4];
        // prologue: tile k0=0
#pragma unroll
        for (int i = 0; i < 4; ++i) {
            int u = i * 512 + tid; int row = u >> 3, kc = u & 7;
            areg[i] = *(const uint4*)&xb[(size_t)toksS[row] * H_DIM + kc * 8];
        }
#pragma unroll
        for (int i = 0; i < 4; ++i)
            breg[i] = *(const float4*)&W[(size_t)(k4 * 4 + i) * (2 * F_DIM) + srcc];

        const int NT = H_DIM / 64;
        for (int kt = 0; kt < NT; ++kt) {
            // write staged regs -> LDS (swizzled)
#pragma unroll
            for (int i = 0; i < 4; ++i) {
                int u = i * 512 + tid; int row = u >> 3, kc = u & 7;
                *(uint4*)&As[row * 64 + ((kc ^ (row & 7)) << 3)] = areg[i];
            }
#pragma unroll
            for (int cc = 0; cc < 4; ++cc) {
                int r = c4 + cc;
                ushort4 p = make_ushort4(
                    f2bf(((const float*)&breg[0])[cc]),
                    f2bf(((const float*)&breg[1])[cc]),
                    f2bf(((const float*)&breg[2])[cc]),
                    f2bf(((const float*)&breg[3])[cc]));
                *(ushort4*)&Bs[r * 64 + (((k4 >> 1) ^ (r & 7)) << 3) + (k4 & 1) * 4] = p;
            }
            __syncthreads();
            if (kt + 1 < NT) {       // prefetch next tile; latency hides under MFMA
                const int k0 = (kt + 1) * 64;
#pragma unroll
                for (int i = 0; i < 4; ++i) {
                    int u = i * 512 + tid; int row = u >> 3, kc = u & 7;
                    areg[i] = *(const uint4*)&xb[(size_t)toksS[row] * H_DIM + k0 + kc * 8];
                }
#pragma unroll
                for (int i = 0; i < 4; ++i)
                    breg[i] = *(const float4*)&W[(size_t)(k0 + k4 * 4 + i) * (2 * F_DIM) + srcc];
            }
#pragma unroll
            for (int ks = 0; ks < 2; ++ks) {
                short8v af[4], bfr[4];
#pragma unroll
                for (int fm = 0; fm < 4; ++fm) {
                    int row = wm * 64 + fm * 16 + lrow;
                    int kc = ks * 4 + lhi;
                    af[fm] = *(const short8v*)&As[row * 64 + ((kc ^ (row & 7)) << 3)];
                }
#pragma unroll
                for (int fn = 0; fn < 4; ++fn) {
                    int r = wn * 64 + fn * 16 + lrow;
                    int kc = ks * 4 + lhi;
                    bfr[fn] = *(const short8v*)&Bs[r * 64 + ((kc ^ (r & 7)) << 3)];
                }
#pragma unroll
                for (int fm = 0; fm < 4; ++fm)
#pragma unroll
                    for (int fn = 0; fn < 4; ++fn)
                        acc[fm][fn] = __builtin_amdgcn_mfma_f32_16x16x32_bf16(
                            af[fm], bfr[fn], acc[fm][fn], 0, 0, 0);
            }
            __syncthreads();
        }

        // epilogue: pair g (fn 0,1) with u (fn 2,3); silu; store bf16
#pragma unroll
        for (int fm = 0; fm < 4; ++fm) {
#pragma unroll
            for (int fl = 0; fl < 2; ++fl) {
                f32x4 g = acc[fm][fl], uu = acc[fm][fl + 2];
#pragma unroll
                for (int i = 0; i < 4; ++i) {
                    int ml = wm * 64 + fm * 16 + lhi * 4 + i;
                    int idx = m0 + ml;
                    if (!ROUTED || idx < ne) {
                        float gv = g[i], uv = uu[i];
                        float s = gv / (1.f + __expf(-gv));
                        float val = s * uv * twsS[ml];
                        int acol = c0 + wn * 32 + fl * 16 + lrow;
                        size_t orow = ROUTED ? (size_t)(base + idx) : (size_t)idx;
                        actout[orow * F_DIM + acol] = f2bf(val);
                    }
                }
            }
        }
    }
}

// ---------------------------------------------------------------------------
// MFMA down-proj. BM=256 rows x 128 out cols, K=512 (BK=64).
// ROUTED: atomicAdd scatter to out[tok]; SHARED(!ROUTED): plain store *sigmoid.
// ---------------------------------------------------------------------------
template<bool ROUTED>
__global__ __launch_bounds__(512, 1) void down_mfma_kernel(
    const unsigned short* __restrict__ actb,
    const float* __restrict__ Wall,
    const int* __restrict__ counts, const int* __restrict__ offsets,
    const int* __restrict__ bucket_tok, const float* __restrict__ sgate,
    float* __restrict__ out)
{
    __shared__ __align__(16) unsigned short As[256 * 64];
    __shared__ __align__(16) unsigned short Bs[128 * 64];
    __shared__ int   toksS[256];
    __shared__ float sgS[256];

    const int tid  = threadIdx.x;
    const int lane = tid & 63;
    const int wid  = tid >> 6;
    const int wm = wid >> 1, wn = wid & 1;
    const int lrow = lane & 15, lhi = lane >> 4;

    const int c0 = blockIdx.x * 128;
    int ne, base, m0_init, m_end;
    const float* W;
    if (ROUTED) {
        int e = blockIdx.y;
        ne = counts[e]; base = offsets[e];
        m0_init = 0; m_end = ne;
        W = Wall + (size_t)e * F_DIM * H_DIM;
    } else {
        ne = T_TOK; base = 0;
        m0_init = blockIdx.y * 256; m_end = m0_init + 256;
        W = Wall;
    }

    const int c4 = (tid & 31) * 4;
    const int k4 = tid >> 5;
    const int srcc = c0 + c4;

    for (int m0 = m0_init; m0 < m_end; m0 += 256) {
        __syncthreads();
        if (tid < 256) {
            if (ROUTED) {
                int idx = m0 + tid;
                toksS[tid] = (idx < ne) ? bucket_tok[base + idx] : 0;
            } else {
                sgS[tid] = sgate[m0 + tid];
            }
        }
        __syncthreads();

        f32x4 acc[4][4];
#pragma unroll
        for (int i = 0; i < 4; ++i)
#pragma unroll
            for (int j = 0; j < 4; ++j) acc[i][j] = (f32x4){0.f, 0.f, 0.f, 0.f};

        uint4  areg[4];
        float4 breg[4];
#pragma unroll
        for (int i = 0; i < 4; ++i) {
            int u = i * 512 + tid; int row = u >> 3, kc = u & 7;
            int grow = ROUTED ? min(base + m0 + row, NROWS - 1) : (m0 + row);
            areg[i] = *(const uint4*)&actb[(size_t)grow * F_DIM + kc * 8];
        }
#pragma unroll
        for (int i = 0; i < 4; ++i)
            breg[i] = *(const float4*)&W[(size_t)(k4 * 4 + i) * H_DIM + srcc];

        const int NT = F_DIM / 64;
        for (int kt = 0; kt < NT; ++kt) {
#pragma unroll
            for (int i = 0; i < 4; ++i) {
                int u = i * 512 + tid; int row = u >> 3, kc = u & 7;
                *(uint4*)&As[row * 64 + ((kc ^ (row & 7)) << 3)] = areg[i];
            }
#pragma unroll
            for (int cc = 0; cc < 4; ++cc) {
                int r = c4 + cc;
                ushort4 p = make_ushort4(
                    f2bf(((const float*)&breg[0])[cc]),
                    f2bf(((const float*)&breg[1])[cc]),
                    f2bf(((const float*)&breg[2])[cc]),
                    f2bf(((const float*)&breg[3])[cc]));
                *(ushort4*)&Bs[r * 64 + (((k4 >> 1) ^ (r & 7)) << 3) + (k4 & 1) * 4] = p;
            }
            __syncthreads();
            if (kt + 1 < NT) {
                const int k0 = (kt + 1) * 64;
#pragma unroll
                for (int i = 0; i < 4; ++i) {
                    int u = i * 512 + tid; int row = u >> 3, kc = u & 7;
                    int grow = ROUTED ? min(base + m0 + row, NROWS - 1) : (m0 + row);
                    areg[i] = *(const uint4*)&actb[(size_t)grow * F_DIM + k0 + kc * 8];
                }
#pragma unroll
                for (int i = 0; i < 4; ++i)
                    breg[i] = *(const float4*)&W[(size_t)(k0 + k4 * 4 + i) * H_DIM + srcc];
            }
#pragma unroll
            for (int ks = 0; ks < 2; ++ks) {
                short8v af[4], bfr[4];
#pragma unroll
                for (int fm = 0; fm < 4; ++fm) {
                    int row = wm * 64 + fm * 16 + lrow;
                    int kc = ks * 4 + lhi;
                    af[fm] = *(const short8v*)&As[row * 64 + ((kc ^ (row & 7)) << 3)];
                }
#pragma unroll
                for (int fn = 0; fn < 4; ++fn) {
                    int r = wn * 64 + fn * 16 + lrow;
                    int kc = ks * 4 + lhi;
                    bfr[fn] = *(const short8v*)&Bs[r * 64 + ((kc ^ (r & 7)) << 3)];
                }
#pragma unroll
                for (int fm = 0; fm < 4; ++fm)
#pragma unroll
                    for (int fn = 0; fn < 4; ++fn)
                        acc[fm][fn] = __builtin_amdgcn_mfma_f32_16x16x32_bf16(
                            af[fm], bfr[fn], acc[fm][fn], 0, 0, 0);
            }
            __syncthreads();
        }

#pragma unroll
        for (int fm = 0; fm < 4; ++fm) {
#pragma unroll
            for (int fn = 0; fn < 4; ++fn) {
#pragma unroll
                for (int i = 0; i < 4; ++i) {
                    int ml = wm * 64 + fm * 16 + lhi * 4 + i;
                    int idx = m0 + ml;
                    int col = c0 + wn * 64 + fn * 16 + lrow;
                    if (ROUTED) {
                        if (idx < ne)
                            atomicAdd(&out[(size_t)toksS[ml] * H_DIM + col], acc[fm][fn][i]);
                    } else {
                        out[(size_t)idx * H_DIM + col] = sgS[ml] * acc[fm][fn][i];
                    }
                }
            }
        }
    }
}

// ---------------------------------------------------------------------------
extern "C" void kernel_launch(void* const* d_in, const int* in_sizes, int n_in,
                              void* d_out, int out_size, void* d_ws, size_t ws_size,
                              hipStream_t stream) {
    const float* x    = (const float*)d_in[0];
    const float* Wg   = (const float*)d_in[1];
    const float* Wgu  = (const float*)d_in[2];
    const float* Wd   = (const float*)d_in[3];
    const float* Wsgu = (const float*)d_in[4];
    const float* Wsd  = (const float*)d_in[5];
    float* out = (float*)d_out;

    char* p = (char*)d_ws;
    auto alloc = [&](size_t bytes) {
        char* r = p;
        p += (bytes + 255) & ~(size_t)255;
        return r;
    };
    int*   topk_idx   = (int*)  alloc((size_t)T_TOK * K_TOP * sizeof(int));
    float* topk_w     = (float*)alloc((size_t)T_TOK * K_TOP * sizeof(float));
    float* sgate      = (float*)alloc((size_t)T_TOK * sizeof(float));
    int*   counts     = (int*)  alloc((size_t)E_NUM * sizeof(int));
    int*   offsets    = (int*)  alloc((size_t)E_NUM * sizeof(int));
    int*   bucket_tok = (int*)  alloc((size_t)NROWS * sizeof(int));
    float* bucket_w   = (float*)alloc((size_t)NROWS * sizeof(float));
    unsigned short* xb    = (unsigned short*)alloc((size_t)T_TOK * H_DIM * sizeof(short));
    unsigned short* act_r = (unsigned short*)alloc((size_t)NROWS * F_DIM * sizeof(short));
    unsigned short* act_s = (unsigned short*)alloc((size_t)T_TOK * FS_DIM * sizeof(short));

    hipMemsetAsync(counts, 0, E_NUM * sizeof(int), stream);
    cvt_bf16_kernel<<<(T_TOK * H_DIM / 8 + 255) / 256, 256, 0, stream>>>(x, xb, T_TOK * H_DIM / 8);
    router_kernel<<<T_TOK, 64, 0, stream>>>(x, Wg, topk_idx, topk_w, sgate, counts);
    bucket_kernel<<<E_NUM, 256, 0, stream>>>(topk_idx, topk_w, counts, offsets, bucket_tok, bucket_w);

    gu_mfma_kernel<true><<<dim3(8, E_NUM), 512, 0, stream>>>(
        xb, Wgu, counts, offsets, bucket_tok, bucket_w, act_r);
    gu_mfma_kernel<false><<<dim3(8, T_TOK / 256), 512, 0, stream>>>(
        xb, Wsgu, counts, offsets, bucket_tok, bucket_w, act_s);

    // shared writes out first; routed atomically accumulates on top
    down_mfma_kernel<false><<<dim3(16, T_TOK / 256), 512, 0, stream>>>(
        act_s, Wsd, counts, offsets, bucket_tok, sgate, out);
    down_mfma_kernel<true><<<dim3(16, E_NUM), 512, 0, stream>>>(
        act_r, Wd, counts, offsets, bucket_tok, sgate, out);
}

// Round 3
// 865.976 us; speedup vs baseline: 8.8532x; 1.1593x over previous
//
#include <hip/hip_runtime.h>
#include <hip/hip_bf16.h>
#include <math.h>

#define T_TOK 2048
#define H_DIM 2048
#define E_NUM 64
#define F_DIM 512
#define K_TOP 8
#define FS_DIM 512
#define NROWS (T_TOK * K_TOP)

typedef __attribute__((ext_vector_type(8))) short short8v;   // bf16x8 MFMA frag
typedef __attribute__((ext_vector_type(4))) float f32x4;     // MFMA accum

static __device__ __forceinline__ unsigned short f2bf(float f) {
    unsigned int u = __float_as_uint(f);
    u += 0x7fff + ((u >> 16) & 1);           // RNE to bf16
    return (unsigned short)(u >> 16);
}

// ---------------------------------------------------------------------------
// x (fp32) -> bf16 copy, vectorized 8/thread
// ---------------------------------------------------------------------------
__global__ __launch_bounds__(256) void cvt_bf16_kernel(
    const float* __restrict__ in, unsigned short* __restrict__ out, int n8)
{
    int i = blockIdx.x * 256 + threadIdx.x;
    if (i < n8) {
        const float4* p = (const float4*)(in + (size_t)i * 8);
        float4 v0 = p[0], v1 = p[1];
        ushort4 a = make_ushort4(f2bf(v0.x), f2bf(v0.y), f2bf(v0.z), f2bf(v0.w));
        ushort4 b = make_ushort4(f2bf(v1.x), f2bf(v1.y), f2bf(v1.z), f2bf(v1.w));
        ushort4* q = (ushort4*)(out + (size_t)i * 8);
        q[0] = a; q[1] = b;
    }
}

// ---------------------------------------------------------------------------
// Router: one wave per token (fp32 math, exact top-k vs reference).
// ---------------------------------------------------------------------------
__global__ __launch_bounds__(64) void router_kernel(
    const float* __restrict__ x, const float* __restrict__ Wg,
    int* __restrict__ topk_idx, float* __restrict__ topk_w,
    float* __restrict__ sgate, int* __restrict__ counts)
{
    const int t = blockIdx.x;
    const int lane = threadIdx.x;
    const float* xr = x + (size_t)t * H_DIM;

    float a0 = 0.f, a1 = 0.f, a2 = 0.f, a3 = 0.f;
    for (int h = 0; h < H_DIM; h += 4) {
        float4 xv = *(const float4*)&xr[h];
        a0 += xv.x * Wg[(h + 0) * 65 + lane];
        a1 += xv.y * Wg[(h + 1) * 65 + lane];
        a2 += xv.z * Wg[(h + 2) * 65 + lane];
        a3 += xv.w * Wg[(h + 3) * 65 + lane];
    }
    float logit = (a0 + a1) + (a2 + a3);

    float a64 = 0.f;
    for (int h = lane; h < H_DIM; h += 64) a64 += xr[h] * Wg[h * 65 + 64];
#pragma unroll
    for (int off = 32; off >= 1; off >>= 1) a64 += __shfl_xor(a64, off);

    float v = logit;
    float selv[K_TOP]; int seli[K_TOP];
#pragma unroll
    for (int k = 0; k < K_TOP; ++k) {
        float mv = v; int mi = lane;
#pragma unroll
        for (int off = 32; off >= 1; off >>= 1) {
            float ov = __shfl_xor(mv, off);
            int   oi = __shfl_xor(mi, off);
            if (ov > mv || (ov == mv && oi < mi)) { mv = ov; mi = oi; }
        }
        selv[k] = mv; seli[k] = mi;
        if (lane == mi) v = -INFINITY;
    }

    if (lane == 0) {
        float m = selv[0];
        float w[K_TOP]; float s = 0.f;
#pragma unroll
        for (int k = 0; k < K_TOP; ++k) { w[k] = __expf(selv[k] - m); s += w[k]; }
        float inv = 1.f / s;
#pragma unroll
        for (int k = 0; k < K_TOP; ++k) {
            topk_idx[t * K_TOP + k] = seli[k];
            topk_w[t * K_TOP + k] = w[k] * inv;
            atomicAdd(&counts[seli[k]], 1);
        }
        sgate[t] = 1.f / (1.f + __expf(-a64));
    }
}

// ---------------------------------------------------------------------------
// Deterministic per-expert compaction.
// ---------------------------------------------------------------------------
__global__ __launch_bounds__(256) void bucket_kernel(
    const int* __restrict__ topk_idx, const float* __restrict__ topk_w,
    const int* __restrict__ counts, int* __restrict__ offsets,
    int* __restrict__ bucket_tok, float* __restrict__ bucket_w)
{
    const int e = blockIdx.x, thr = threadIdx.x;
    __shared__ int cnt[256];
    __shared__ int base_s;
    const int q0 = thr * 64;
    int c = 0;
    for (int q = 0; q < 64; ++q) c += (topk_idx[q0 + q] == e) ? 1 : 0;
    cnt[thr] = c;
    __syncthreads();
    if (thr == 0) {
        int off = 0;
        for (int i = 0; i < e; ++i) off += counts[i];
        offsets[e] = off;
        base_s = off;
        int run = 0;
        for (int i = 0; i < 256; ++i) { int tval = cnt[i]; cnt[i] = run; run += tval; }
    }
    __syncthreads();
    int pos = base_s + cnt[thr];
    for (int q = 0; q < 64; ++q) {
        int pp = q0 + q;
        if (topk_idx[pp] == e) {
            bucket_tok[pos] = pp >> 3;
            bucket_w[pos] = topk_w[pp];
            ++pos;
        }
    }
}

// ---------------------------------------------------------------------------
// gate_up + SiLU*u*topw. A-frags read DIRECTLY from global bf16 (x is L2/L3
// resident); only W (fp32->bf16 transpose) staged in LDS.
// Block 512 thr = 8 waves (4 wm x 2 wn). Wave tile: FM*16 rows x 16 act cols.
// BM = FM*64. BN_act = 32 (64 W cols: [g wn0|u wn0|g wn1|u wn1] by n-index:
// n = wn*32 + fn*16 + lrow; fn0 = gate, fn1 = up).
// ---------------------------------------------------------------------------
template<int FM, bool ROUTED>
__global__ __launch_bounds__(512, 4) void gu_mfma_kernel(
    const unsigned short* __restrict__ xb,
    const float* __restrict__ Wall,
    const int* __restrict__ counts, const int* __restrict__ offsets,
    const int* __restrict__ bucket_tok, const float* __restrict__ bucket_w,
    unsigned short* __restrict__ actout)
{
    constexpr int BM = FM * 64;
    __shared__ __align__(16) unsigned short Bs[64 * 64];
    __shared__ int   toksS[BM];
    __shared__ float twsS[BM];

    const int tid  = threadIdx.x;
    const int lane = tid & 63;
    const int wid  = tid >> 6;
    const int wm = wid >> 1, wn = wid & 1;
    const int lrow = lane & 15, lhi = lane >> 4;
    const int lr7  = lrow & 7;

    const int c0 = blockIdx.x * 32;        // act-col base
    int ne, base;
    const float* W;
    if (ROUTED) {
        int e = blockIdx.y;
        ne = counts[e]; base = offsets[e];
        W = Wall + (size_t)e * H_DIM * (2 * F_DIM);
    } else {
        ne = T_TOK; base = 0;
        W = Wall;
    }

    // W staging geometry: thread covers 4 n-cols x 2 k-rows (float4 x2)
    const int n4 = (tid & 15) * 4;         // Bs n-row base
    const int kb = (tid >> 4) * 2;         // k base (0..62)
    const int n5 = n4 & 31;
    const int wcol = ((n5 < 16) ? 0 : (F_DIM - 16)) + c0 + (n4 >> 5) * 16 + n5;

    const int m0_beg = ROUTED ? 0 : blockIdx.y * BM;
    const int m0_end = ROUTED ? ne : m0_beg + BM;

    for (int m0 = m0_beg; m0 < m0_end; m0 += BM) {
        __syncthreads();
        for (int i = tid; i < BM; i += 512) {
            if (ROUTED) {
                int idx = m0 + i; bool v = idx < ne;
                toksS[i] = v ? bucket_tok[base + idx] : bucket_tok[base];
                twsS[i]  = v ? bucket_w[base + idx] : 0.f;
            } else {
                toksS[i] = m0 + i; twsS[i] = 1.f;
            }
        }
        __syncthreads();

        // per-lane A row pointers (direct-global frags)
        const unsigned short* aptr[FM];
#pragma unroll
        for (int fm = 0; fm < FM; ++fm) {
            int r = wm * (FM * 16) + fm * 16 + lrow;
            aptr[fm] = xb + (size_t)toksS[r] * H_DIM;
        }

        f32x4 acc[FM][2];
#pragma unroll
        for (int i = 0; i < FM; ++i) {
            acc[i][0] = (f32x4){0.f, 0.f, 0.f, 0.f};
            acc[i][1] = (f32x4){0.f, 0.f, 0.f, 0.f};
        }

        float4 b0 = *(const float4*)&W[(size_t)kb * (2 * F_DIM) + wcol];
        float4 b1 = *(const float4*)&W[(size_t)(kb + 1) * (2 * F_DIM) + wcol];

        const int NT = H_DIM / 64;
        for (int kt = 0; kt < NT; ++kt) {
            // transpose-write staged W regs -> LDS bf16 (16B-chunk XOR swizzle)
#pragma unroll
            for (int cc = 0; cc < 4; ++cc) {
                int n = n4 + cc;
                int idx = n * 64 + ((((kb >> 3) ^ (n & 7)) << 3)) + (kb & 7);
                ushort2 p = make_ushort2(f2bf(((const float*)&b0)[cc]),
                                         f2bf(((const float*)&b1)[cc]));
                *(ushort2*)&Bs[idx] = p;
            }
            __syncthreads();
            if (kt + 1 < NT) {
                const int k0n = (kt + 1) * 64;
                b0 = *(const float4*)&W[(size_t)(k0n + kb) * (2 * F_DIM) + wcol];
                b1 = *(const float4*)&W[(size_t)(k0n + kb + 1) * (2 * F_DIM) + wcol];
            }
            const int k0 = kt * 64;
#pragma unroll
            for (int ks = 0; ks < 2; ++ks) {
                const int kc = ks * 4 + lhi;
                short8v bg = *(const short8v*)&Bs[(wn * 32 + lrow) * 64 + ((kc ^ lr7) << 3)];
                short8v bu = *(const short8v*)&Bs[(wn * 32 + 16 + lrow) * 64 + ((kc ^ lr7) << 3)];
                const int koff = k0 + kc * 8;
#pragma unroll
                for (int fm = 0; fm < FM; ++fm) {
                    short8v af = *(const short8v*)(aptr[fm] + koff);
                    acc[fm][0] = __builtin_amdgcn_mfma_f32_16x16x32_bf16(af, bg, acc[fm][0], 0, 0, 0);
                    acc[fm][1] = __builtin_amdgcn_mfma_f32_16x16x32_bf16(af, bu, acc[fm][1], 0, 0, 0);
                }
            }
            __syncthreads();
        }

        // epilogue: silu(g)*u*topw -> bf16 act
        const int acol = c0 + wn * 16 + lrow;
#pragma unroll
        for (int fm = 0; fm < FM; ++fm) {
#pragma unroll
            for (int i = 0; i < 4; ++i) {
                int ml = wm * (FM * 16) + fm * 16 + lhi * 4 + i;
                int idx = m0 + ml;
                if (!ROUTED || idx < ne) {
                    float gv = acc[fm][0][i], uv = acc[fm][1][i];
                    float s = gv / (1.f + __expf(-gv));
                    float val = s * uv * twsS[ml];
                    size_t orow = ROUTED ? (size_t)(base + idx) : (size_t)idx;
                    actout[orow * F_DIM + acol] = f2bf(val);
                }
            }
        }
    }
}

// ---------------------------------------------------------------------------
// down-proj. A-frags direct from bf16 act (packed rows). W staged via LDS.
// Block 512 = 8 waves (4 wm x 2 wn). BN = 64 out cols; n = wn*32 + fn*16 + lrow.
// ROUTED: atomicAdd scatter onto out; shared: plain store * sigmoid.
// ---------------------------------------------------------------------------
template<int FM, bool ROUTED>
__global__ __launch_bounds__(512, 4) void down_mfma_kernel(
    const unsigned short* __restrict__ actb,
    const float* __restrict__ Wall,
    const int* __restrict__ counts, const int* __restrict__ offsets,
    const int* __restrict__ bucket_tok, const float* __restrict__ sgate,
    float* __restrict__ out)
{
    constexpr int BM = FM * 64;
    __shared__ __align__(16) unsigned short Bs[64 * 64];
    __shared__ int   toksS[BM];
    __shared__ float sgS[BM];

    const int tid  = threadIdx.x;
    const int lane = tid & 63;
    const int wid  = tid >> 6;
    const int wm = wid >> 1, wn = wid & 1;
    const int lrow = lane & 15, lhi = lane >> 4;
    const int lr7  = lrow & 7;

    const int c0 = blockIdx.x * 64;
    int ne, base;
    const float* W;
    if (ROUTED) {
        int e = blockIdx.y;
        ne = counts[e]; base = offsets[e];
        W = Wall + (size_t)e * F_DIM * H_DIM;
    } else {
        ne = T_TOK; base = 0;
        W = Wall;
    }

    const int n4 = (tid & 15) * 4;
    const int kb = (tid >> 4) * 2;
    const int wcol = c0 + n4;

    const int m0_beg = ROUTED ? 0 : blockIdx.y * BM;
    const int m0_end = ROUTED ? ne : m0_beg + BM;

    for (int m0 = m0_beg; m0 < m0_end; m0 += BM) {
        __syncthreads();
        for (int i = tid; i < BM; i += 512) {
            if (ROUTED) {
                int idx = m0 + i;
                toksS[i] = (idx < ne) ? bucket_tok[base + idx] : 0;
            } else {
                sgS[i] = sgate[m0 + i];
            }
        }
        __syncthreads();

        const unsigned short* aptr[FM];
#pragma unroll
        for (int fm = 0; fm < FM; ++fm) {
            int r = wm * (FM * 16) + fm * 16 + lrow;
            int grow = ROUTED ? min(base + m0 + r, NROWS - 1) : (m0 + r);
            aptr[fm] = actb + (size_t)grow * F_DIM;
        }

        f32x4 acc[FM][2];
#pragma unroll
        for (int i = 0; i < FM; ++i) {
            acc[i][0] = (f32x4){0.f, 0.f, 0.f, 0.f};
            acc[i][1] = (f32x4){0.f, 0.f, 0.f, 0.f};
        }

        float4 b0 = *(const float4*)&W[(size_t)kb * H_DIM + wcol];
        float4 b1 = *(const float4*)&W[(size_t)(kb + 1) * H_DIM + wcol];

        const int NT = F_DIM / 64;
        for (int kt = 0; kt < NT; ++kt) {
#pragma unroll
            for (int cc = 0; cc < 4; ++cc) {
                int n = n4 + cc;
                int idx = n * 64 + ((((kb >> 3) ^ (n & 7)) << 3)) + (kb & 7);
                ushort2 p = make_ushort2(f2bf(((const float*)&b0)[cc]),
                                         f2bf(((const float*)&b1)[cc]));
                *(ushort2*)&Bs[idx] = p;
            }
            __syncthreads();
            if (kt + 1 < NT) {
                const int k0n = (kt + 1) * 64;
                b0 = *(const float4*)&W[(size_t)(k0n + kb) * H_DIM + wcol];
                b1 = *(const float4*)&W[(size_t)(k0n + kb + 1) * H_DIM + wcol];
            }
            const int k0 = kt * 64;
#pragma unroll
            for (int ks = 0; ks < 2; ++ks) {
                const int kc = ks * 4 + lhi;
                short8v bf0 = *(const short8v*)&Bs[(wn * 32 + lrow) * 64 + ((kc ^ lr7) << 3)];
                short8v bf1 = *(const short8v*)&Bs[(wn * 32 + 16 + lrow) * 64 + ((kc ^ lr7) << 3)];
                const int koff = k0 + kc * 8;
#pragma unroll
                for (int fm = 0; fm < FM; ++fm) {
                    short8v af = *(const short8v*)(aptr[fm] + koff);
                    acc[fm][0] = __builtin_amdgcn_mfma_f32_16x16x32_bf16(af, bf0, acc[fm][0], 0, 0, 0);
                    acc[fm][1] = __builtin_amdgcn_mfma_f32_16x16x32_bf16(af, bf1, acc[fm][1], 0, 0, 0);
                }
            }
            __syncthreads();
        }

#pragma unroll
        for (int fm = 0; fm < FM; ++fm) {
#pragma unroll
            for (int fn = 0; fn < 2; ++fn) {
                int col = c0 + wn * 32 + fn * 16 + lrow;
#pragma unroll
                for (int i = 0; i < 4; ++i) {
                    int ml = wm * (FM * 16) + fm * 16 + lhi * 4 + i;
                    int idx = m0 + ml;
                    if (ROUTED) {
                        if (idx < ne)
                            atomicAdd(&out[(size_t)toksS[ml] * H_DIM + col], acc[fm][fn][i]);
                    } else {
                        out[(size_t)idx * H_DIM + col] = sgS[ml] * acc[fm][fn][i];
                    }
                }
            }
        }
    }
}

// ---------------------------------------------------------------------------
extern "C" void kernel_launch(void* const* d_in, const int* in_sizes, int n_in,
                              void* d_out, int out_size, void* d_ws, size_t ws_size,
                              hipStream_t stream) {
    const float* x    = (const float*)d_in[0];
    const float* Wg   = (const float*)d_in[1];
    const float* Wgu  = (const float*)d_in[2];
    const float* Wd   = (const float*)d_in[3];
    const float* Wsgu = (const float*)d_in[4];
    const float* Wsd  = (const float*)d_in[5];
    float* out = (float*)d_out;

    char* p = (char*)d_ws;
    auto alloc = [&](size_t bytes) {
        char* r = p;
        p += (bytes + 255) & ~(size_t)255;
        return r;
    };
    int*   topk_idx   = (int*)  alloc((size_t)T_TOK * K_TOP * sizeof(int));
    float* topk_w     = (float*)alloc((size_t)T_TOK * K_TOP * sizeof(float));
    float* sgate      = (float*)alloc((size_t)T_TOK * sizeof(float));
    int*   counts     = (int*)  alloc((size_t)E_NUM * sizeof(int));
    int*   offsets    = (int*)  alloc((size_t)E_NUM * sizeof(int));
    int*   bucket_tok = (int*)  alloc((size_t)NROWS * sizeof(int));
    float* bucket_w   = (float*)alloc((size_t)NROWS * sizeof(float));
    unsigned short* xb    = (unsigned short*)alloc((size_t)T_TOK * H_DIM * sizeof(short));
    unsigned short* act_r = (unsigned short*)alloc((size_t)NROWS * F_DIM * sizeof(short));
    unsigned short* act_s = (unsigned short*)alloc((size_t)T_TOK * FS_DIM * sizeof(short));

    hipMemsetAsync(counts, 0, E_NUM * sizeof(int), stream);
    cvt_bf16_kernel<<<(T_TOK * H_DIM / 8 + 255) / 256, 256, 0, stream>>>(x, xb, T_TOK * H_DIM / 8);
    router_kernel<<<T_TOK, 64, 0, stream>>>(x, Wg, topk_idx, topk_w, sgate, counts);
    bucket_kernel<<<E_NUM, 256, 0, stream>>>(topk_idx, topk_w, counts, offsets, bucket_tok, bucket_w);

    // routed gate_up: BM=320 (one m-pass for ne<=320), W streamed once
    gu_mfma_kernel<5, true><<<dim3(16, E_NUM), 512, 0, stream>>>(
        xb, Wgu, counts, offsets, bucket_tok, bucket_w, act_r);
    // shared gate_up: BM=128, 16 m-tiles
    gu_mfma_kernel<2, false><<<dim3(16, T_TOK / 128), 512, 0, stream>>>(
        xb, Wsgu, counts, offsets, bucket_tok, bucket_w, act_s);

    // shared down writes out first; routed down accumulates atomically on top
    down_mfma_kernel<2, false><<<dim3(32, T_TOK / 128), 512, 0, stream>>>(
        act_s, Wsd, counts, offsets, bucket_tok, sgate, out);
    down_mfma_kernel<5, true><<<dim3(32, E_NUM), 512, 0, stream>>>(
        act_r, Wd, counts, offsets, bucket_tok, sgate, out);
}

// Round 5
// 817.685 us; speedup vs baseline: 9.3761x; 1.0591x over previous
//
#include <hip/hip_runtime.h>
#include <hip/hip_bf16.h>
#include <math.h>

#define T_TOK 2048
#define H_DIM 2048
#define E_NUM 64
#define F_DIM 512
#define K_TOP 8
#define FS_DIM 512
#define NROWS (T_TOK * K_TOP)

typedef __attribute__((ext_vector_type(8))) short short8v;   // bf16x8 MFMA frag
typedef __attribute__((ext_vector_type(4))) float f32x4;     // MFMA accum

static __device__ __forceinline__ unsigned short f2bf(float f) {
    unsigned int u = __float_as_uint(f);
    u += 0x7fff + ((u >> 16) & 1);           // RNE to bf16
    return (unsigned short)(u >> 16);
}

// ---------------------------------------------------------------------------
// x (fp32) -> bf16 copy, vectorized 8/thread
// ---------------------------------------------------------------------------
__global__ __launch_bounds__(256) void cvt_bf16_kernel(
    const float* __restrict__ in, unsigned short* __restrict__ out, int n8)
{
    int i = blockIdx.x * 256 + threadIdx.x;
    if (i < n8) {
        const float4* p = (const float4*)(in + (size_t)i * 8);
        float4 v0 = p[0], v1 = p[1];
        ushort4 a = make_ushort4(f2bf(v0.x), f2bf(v0.y), f2bf(v0.z), f2bf(v0.w));
        ushort4 b = make_ushort4(f2bf(v1.x), f2bf(v1.y), f2bf(v1.z), f2bf(v1.w));
        ushort4* q = (ushort4*)(out + (size_t)i * 8);
        q[0] = a; q[1] = b;
    }
}

// ---------------------------------------------------------------------------
// Router: one wave per token (fp32 math, exact top-k vs reference).
// ---------------------------------------------------------------------------
__global__ __launch_bounds__(64) void router_kernel(
    const float* __restrict__ x, const float* __restrict__ Wg,
    int* __restrict__ topk_idx, float* __restrict__ topk_w,
    float* __restrict__ sgate, int* __restrict__ counts)
{
    const int t = blockIdx.x;
    const int lane = threadIdx.x;
    const float* xr = x + (size_t)t * H_DIM;

    float a0 = 0.f, a1 = 0.f, a2 = 0.f, a3 = 0.f;
    for (int h = 0; h < H_DIM; h += 4) {
        float4 xv = *(const float4*)&xr[h];
        a0 += xv.x * Wg[(h + 0) * 65 + lane];
        a1 += xv.y * Wg[(h + 1) * 65 + lane];
        a2 += xv.z * Wg[(h + 2) * 65 + lane];
        a3 += xv.w * Wg[(h + 3) * 65 + lane];
    }
    float logit = (a0 + a1) + (a2 + a3);

    float a64 = 0.f;
    for (int h = lane; h < H_DIM; h += 64) a64 += xr[h] * Wg[h * 65 + 64];
#pragma unroll
    for (int off = 32; off >= 1; off >>= 1) a64 += __shfl_xor(a64, off);

    float v = logit;
    float selv[K_TOP]; int seli[K_TOP];
#pragma unroll
    for (int k = 0; k < K_TOP; ++k) {
        float mv = v; int mi = lane;
#pragma unroll
        for (int off = 32; off >= 1; off >>= 1) {
            float ov = __shfl_xor(mv, off);
            int   oi = __shfl_xor(mi, off);
            if (ov > mv || (ov == mv && oi < mi)) { mv = ov; mi = oi; }
        }
        selv[k] = mv; seli[k] = mi;
        if (lane == mi) v = -INFINITY;
    }

    if (lane == 0) {
        float m = selv[0];
        float w[K_TOP]; float s = 0.f;
#pragma unroll
        for (int k = 0; k < K_TOP; ++k) { w[k] = __expf(selv[k] - m); s += w[k]; }
        float inv = 1.f / s;
#pragma unroll
        for (int k = 0; k < K_TOP; ++k) {
            topk_idx[t * K_TOP + k] = seli[k];
            topk_w[t * K_TOP + k] = w[k] * inv;
            atomicAdd(&counts[seli[k]], 1);
        }
        sgate[t] = 1.f / (1.f + __expf(-a64));
    }
}

// ---------------------------------------------------------------------------
// Deterministic per-expert compaction.
// ---------------------------------------------------------------------------
__global__ __launch_bounds__(256) void bucket_kernel(
    const int* __restrict__ topk_idx, const float* __restrict__ topk_w,
    const int* __restrict__ counts, int* __restrict__ offsets,
    int* __restrict__ bucket_tok, float* __restrict__ bucket_w)
{
    const int e = blockIdx.x, thr = threadIdx.x;
    __shared__ int cnt[256];
    __shared__ int base_s;
    const int q0 = thr * 64;
    int c = 0;
    for (int q = 0; q < 64; ++q) c += (topk_idx[q0 + q] == e) ? 1 : 0;
    cnt[thr] = c;
    __syncthreads();
    if (thr == 0) {
        int off = 0;
        for (int i = 0; i < e; ++i) off += counts[i];
        offsets[e] = off;
        base_s = off;
        int run = 0;
        for (int i = 0; i < 256; ++i) { int tval = cnt[i]; cnt[i] = run; run += tval; }
    }
    __syncthreads();
    int pos = base_s + cnt[thr];
    for (int q = 0; q < 64; ++q) {
        int pp = q0 + q;
        if (topk_idx[pp] == e) {
            bucket_tok[pos] = pp >> 3;
            bucket_w[pos] = topk_w[pp];
            ++pos;
        }
    }
}

// ---------------------------------------------------------------------------
// gate_up + SiLU*u*topw. A-frags read DIRECTLY from global bf16 (batched into
// a register array per K-step); only W (fp32->bf16 transpose) staged in LDS,
// double-buffered (1 barrier / K-step), padded stride 72 (conflict-free).
// Block 512 thr = 8 waves (4 wm x 2 wn). BM = FM*64, 32 act cols / block.
// ROUTED: 1D grid, XCD-swizzled so each expert's 16 col-blocks cluster per XCD.
// ---------------------------------------------------------------------------
template<int FM, bool ROUTED>
__global__ __launch_bounds__(512, 4) void gu_mfma_kernel(
    const unsigned short* __restrict__ xb,
    const float* __restrict__ Wall,
    const int* __restrict__ counts, const int* __restrict__ offsets,
    const int* __restrict__ bucket_tok, const float* __restrict__ bucket_w,
    unsigned short* __restrict__ actout)
{
    constexpr int BM = FM * 64;
    constexpr int BST = 72;                 // padded LDS stride (shorts)
    __shared__ __align__(16) unsigned short Bs[2][64 * BST];
    __shared__ int   toksS[BM];
    __shared__ float twsS[BM];

    const int tid  = threadIdx.x;
    const int lane = tid & 63;
    const int wid  = tid >> 6;
    const int wm = wid >> 1, wn = wid & 1;
    const int lrow = lane & 15, lhi = lane >> 4;

    int cblk, ne, base;
    const float* W;
    if (ROUTED) {
        int nw = (blockIdx.x & 7) * ((int)gridDim.x >> 3) + (blockIdx.x >> 3);
        int e = nw >> 4; cblk = nw & 15;
        ne = counts[e]; base = offsets[e];
        W = Wall + (size_t)e * H_DIM * (2 * F_DIM);
    } else {
        cblk = blockIdx.x;
        ne = T_TOK; base = 0;
        W = Wall;
    }
    const int c0 = cblk * 32;               // act-col base

    // W staging geometry: thread covers 4 n-cols x 2 k-rows (float4 x2)
    const int n4 = (tid & 15) * 4;          // Bs n-row base
    const int kb = (tid >> 4) * 2;          // k base (0..62)
    const int n5 = n4 & 31;
    const int wcol = ((n5 < 16) ? 0 : (F_DIM - 16)) + c0 + (n4 >> 5) * 16 + n5;

    const int m0_beg = ROUTED ? 0 : blockIdx.y * BM;
    const int m0_end = ROUTED ? ne : m0_beg + BM;

    for (int m0 = m0_beg; m0 < m0_end; m0 += BM) {
        __syncthreads();
        for (int i = tid; i < BM; i += 512) {
            if (ROUTED) {
                int idx = m0 + i; bool v = idx < ne;
                toksS[i] = v ? bucket_tok[base + idx] : bucket_tok[base];
                twsS[i]  = v ? bucket_w[base + idx] : 0.f;
            } else {
                toksS[i] = m0 + i; twsS[i] = 1.f;
            }
        }
        __syncthreads();

        // per-lane A row pointers (direct-global frags)
        const unsigned short* aptr[FM];
#pragma unroll
        for (int fm = 0; fm < FM; ++fm) {
            int r = wm * (FM * 16) + fm * 16 + lrow;
            aptr[fm] = xb + (size_t)toksS[r] * H_DIM;
        }

        f32x4 acc[FM][2];
#pragma unroll
        for (int i = 0; i < FM; ++i) {
            acc[i][0] = (f32x4){0.f, 0.f, 0.f, 0.f};
            acc[i][1] = (f32x4){0.f, 0.f, 0.f, 0.f};
        }

        // prologue: stage B tile kt=0 into Bs[0]
        {
            float4 b0 = *(const float4*)&W[(size_t)kb * (2 * F_DIM) + wcol];
            float4 b1 = *(const float4*)&W[(size_t)(kb + 1) * (2 * F_DIM) + wcol];
#pragma unroll
            for (int cc = 0; cc < 4; ++cc) {
                ushort2 pk = make_ushort2(f2bf(((const float*)&b0)[cc]),
                                          f2bf(((const float*)&b1)[cc]));
                *(ushort2*)&Bs[0][(n4 + cc) * BST + kb] = pk;
            }
        }
        __syncthreads();

        const int NT = H_DIM / 64;
        for (int kt = 0; kt < NT; ++kt) {
            const int k0 = kt * 64;
            const unsigned short* curB = Bs[kt & 1];
            unsigned short* nxtB = Bs[(kt & 1) ^ 1];

            // batch-load ALL A frags for this K-step (independent loads)
            short8v a[2][FM];
#pragma unroll
            for (int ks = 0; ks < 2; ++ks)
#pragma unroll
                for (int fm = 0; fm < FM; ++fm)
                    a[ks][fm] = *(const short8v*)(aptr[fm] + k0 + (ks * 4 + lhi) * 8);

            // prefetch next B tile into regs (latency hidden under MFMA)
            float4 b0, b1;
            if (kt + 1 < NT) {
                b0 = *(const float4*)&W[(size_t)(k0 + 64 + kb) * (2 * F_DIM) + wcol];
                b1 = *(const float4*)&W[(size_t)(k0 + 64 + kb + 1) * (2 * F_DIM) + wcol];
            }

#pragma unroll
            for (int ks = 0; ks < 2; ++ks) {
                const int kc = ks * 4 + lhi;
                short8v bg = *(const short8v*)&curB[(wn * 32 + lrow) * BST + kc * 8];
                short8v bu = *(const short8v*)&curB[(wn * 32 + 16 + lrow) * BST + kc * 8];
#pragma unroll
                for (int fm = 0; fm < FM; ++fm) {
                    acc[fm][0] = __builtin_amdgcn_mfma_f32_16x16x32_bf16(a[ks][fm], bg, acc[fm][0], 0, 0, 0);
                    acc[fm][1] = __builtin_amdgcn_mfma_f32_16x16x32_bf16(a[ks][fm], bu, acc[fm][1], 0, 0, 0);
                }
            }

            if (kt + 1 < NT) {
#pragma unroll
                for (int cc = 0; cc < 4; ++cc) {
                    ushort2 pk = make_ushort2(f2bf(((const float*)&b0)[cc]),
                                              f2bf(((const float*)&b1)[cc]));
                    *(ushort2*)&nxtB[(n4 + cc) * BST + kb] = pk;
                }
            }
            __syncthreads();
        }

        // epilogue: silu(g)*u*topw -> bf16 act
        const int acol = c0 + wn * 16 + lrow;
#pragma unroll
        for (int fm = 0; fm < FM; ++fm) {
#pragma unroll
            for (int i = 0; i < 4; ++i) {
                int ml = wm * (FM * 16) + fm * 16 + lhi * 4 + i;
                int idx = m0 + ml;
                if (!ROUTED || idx < ne) {
                    float gv = acc[fm][0][i], uv = acc[fm][1][i];
                    float s = gv / (1.f + __expf(-gv));
                    float val = s * uv * twsS[ml];
                    size_t orow = ROUTED ? (size_t)(base + idx) : (size_t)idx;
                    actout[orow * F_DIM + acol] = f2bf(val);
                }
            }
        }
    }
}

// ---------------------------------------------------------------------------
// down-proj. A-frags direct from bf16 act rows (batched regs); W via LDS
// double-buffer, padded stride. ROUTED: atomicAdd scatter; shared: store*sig.
// ---------------------------------------------------------------------------
template<int FM, bool ROUTED>
__global__ __launch_bounds__(512, 4) void down_mfma_kernel(
    const unsigned short* __restrict__ actb,
    const float* __restrict__ Wall,
    const int* __restrict__ counts, const int* __restrict__ offsets,
    const int* __restrict__ bucket_tok, const float* __restrict__ sgate,
    float* __restrict__ out)
{
    constexpr int BM = FM * 64;
    constexpr int BST = 72;
    __shared__ __align__(16) unsigned short Bs[2][64 * BST];
    __shared__ int   toksS[BM];
    __shared__ float sgS[BM];

    const int tid  = threadIdx.x;
    const int lane = tid & 63;
    const int wid  = tid >> 6;
    const int wm = wid >> 1, wn = wid & 1;
    const int lrow = lane & 15, lhi = lane >> 4;

    int cblk, ne, base;
    const float* W;
    if (ROUTED) {
        int nw = (blockIdx.x & 7) * ((int)gridDim.x >> 3) + (blockIdx.x >> 3);
        int e = nw >> 5; cblk = nw & 31;
        ne = counts[e]; base = offsets[e];
        W = Wall + (size_t)e * F_DIM * H_DIM;
    } else {
        cblk = blockIdx.x;
        ne = T_TOK; base = 0;
        W = Wall;
    }
    const int c0 = cblk * 64;

    const int n4 = (tid & 15) * 4;
    const int kb = (tid >> 4) * 2;
    const int wcol = c0 + n4;

    const int m0_beg = ROUTED ? 0 : blockIdx.y * BM;
    const int m0_end = ROUTED ? ne : m0_beg + BM;

    for (int m0 = m0_beg; m0 < m0_end; m0 += BM) {
        __syncthreads();
        for (int i = tid; i < BM; i += 512) {
            if (ROUTED) {
                int idx = m0 + i;
                toksS[i] = (idx < ne) ? bucket_tok[base + idx] : 0;
            } else {
                sgS[i] = sgate[m0 + i];
            }
        }
        __syncthreads();

        const unsigned short* aptr[FM];
#pragma unroll
        for (int fm = 0; fm < FM; ++fm) {
            int r = wm * (FM * 16) + fm * 16 + lrow;
            int grow = ROUTED ? min(base + m0 + r, NROWS - 1) : (m0 + r);
            aptr[fm] = actb + (size_t)grow * F_DIM;
        }

        f32x4 acc[FM][2];
#pragma unroll
        for (int i = 0; i < FM; ++i) {
            acc[i][0] = (f32x4){0.f, 0.f, 0.f, 0.f};
            acc[i][1] = (f32x4){0.f, 0.f, 0.f, 0.f};
        }

        {
            float4 b0 = *(const float4*)&W[(size_t)kb * H_DIM + wcol];
            float4 b1 = *(const float4*)&W[(size_t)(kb + 1) * H_DIM + wcol];
#pragma unroll
            for (int cc = 0; cc < 4; ++cc) {
                ushort2 pk = make_ushort2(f2bf(((const float*)&b0)[cc]),
                                          f2bf(((const float*)&b1)[cc]));
                *(ushort2*)&Bs[0][(n4 + cc) * BST + kb] = pk;
            }
        }
        __syncthreads();

        const int NT = F_DIM / 64;
        for (int kt = 0; kt < NT; ++kt) {
            const int k0 = kt * 64;
            const unsigned short* curB = Bs[kt & 1];
            unsigned short* nxtB = Bs[(kt & 1) ^ 1];

            short8v a[2][FM];
#pragma unroll
            for (int ks = 0; ks < 2; ++ks)
#pragma unroll
                for (int fm = 0; fm < FM; ++fm)
                    a[ks][fm] = *(const short8v*)(aptr[fm] + k0 + (ks * 4 + lhi) * 8);

            float4 b0, b1;
            if (kt + 1 < NT) {
                b0 = *(const float4*)&W[(size_t)(k0 + 64 + kb) * H_DIM + wcol];
                b1 = *(const float4*)&W[(size_t)(k0 + 64 + kb + 1) * H_DIM + wcol];
            }

#pragma unroll
            for (int ks = 0; ks < 2; ++ks) {
                const int kc = ks * 4 + lhi;
                short8v bf0 = *(const short8v*)&curB[(wn * 32 + lrow) * BST + kc * 8];
                short8v bf1 = *(const short8v*)&curB[(wn * 32 + 16 + lrow) * BST + kc * 8];
#pragma unroll
                for (int fm = 0; fm < FM; ++fm) {
                    acc[fm][0] = __builtin_amdgcn_mfma_f32_16x16x32_bf16(a[ks][fm], bf0, acc[fm][0], 0, 0, 0);
                    acc[fm][1] = __builtin_amdgcn_mfma_f32_16x16x32_bf16(a[ks][fm], bf1, acc[fm][1], 0, 0, 0);
                }
            }

            if (kt + 1 < NT) {
#pragma unroll
                for (int cc = 0; cc < 4; ++cc) {
                    ushort2 pk = make_ushort2(f2bf(((const float*)&b0)[cc]),
                                              f2bf(((const float*)&b1)[cc]));
                    *(ushort2*)&nxtB[(n4 + cc) * BST + kb] = pk;
                }
            }
            __syncthreads();
        }

#pragma unroll
        for (int fm = 0; fm < FM; ++fm) {
#pragma unroll
            for (int fn = 0; fn < 2; ++fn) {
                int col = c0 + wn * 32 + fn * 16 + lrow;
#pragma unroll
                for (int i = 0; i < 4; ++i) {
                    int ml = wm * (FM * 16) + fm * 16 + lhi * 4 + i;
                    int idx = m0 + ml;
                    if (ROUTED) {
                        if (idx < ne)
                            atomicAdd(&out[(size_t)toksS[ml] * H_DIM + col], acc[fm][fn][i]);
                    } else {
                        out[(size_t)idx * H_DIM + col] = sgS[ml] * acc[fm][fn][i];
                    }
                }
            }
        }
    }
}

// ---------------------------------------------------------------------------
extern "C" void kernel_launch(void* const* d_in, const int* in_sizes, int n_in,
                              void* d_out, int out_size, void* d_ws, size_t ws_size,
                              hipStream_t stream) {
    const float* x    = (const float*)d_in[0];
    const float* Wg   = (const float*)d_in[1];
    const float* Wgu  = (const float*)d_in[2];
    const float* Wd   = (const float*)d_in[3];
    const float* Wsgu = (const float*)d_in[4];
    const float* Wsd  = (const float*)d_in[5];
    float* out = (float*)d_out;

    char* p = (char*)d_ws;
    auto alloc = [&](size_t bytes) {
        char* r = p;
        p += (bytes + 255) & ~(size_t)255;
        return r;
    };
    int*   topk_idx   = (int*)  alloc((size_t)T_TOK * K_TOP * sizeof(int));
    float* topk_w     = (float*)alloc((size_t)T_TOK * K_TOP * sizeof(float));
    float* sgate      = (float*)alloc((size_t)T_TOK * sizeof(float));
    int*   counts     = (int*)  alloc((size_t)E_NUM * sizeof(int));
    int*   offsets    = (int*)  alloc((size_t)E_NUM * sizeof(int));
    int*   bucket_tok = (int*)  alloc((size_t)NROWS * sizeof(int));
    float* bucket_w   = (float*)alloc((size_t)NROWS * sizeof(float));
    unsigned short* xb    = (unsigned short*)alloc((size_t)T_TOK * H_DIM * sizeof(short));
    unsigned short* act_r = (unsigned short*)alloc((size_t)NROWS * F_DIM * sizeof(short));
    unsigned short* act_s = (unsigned short*)alloc((size_t)T_TOK * FS_DIM * sizeof(short));

    hipMemsetAsync(counts, 0, E_NUM * sizeof(int), stream);
    cvt_bf16_kernel<<<(T_TOK * H_DIM / 8 + 255) / 256, 256, 0, stream>>>(x, xb, T_TOK * H_DIM / 8);
    router_kernel<<<T_TOK, 64, 0, stream>>>(x, Wg, topk_idx, topk_w, sgate, counts);
    bucket_kernel<<<E_NUM, 256, 0, stream>>>(topk_idx, topk_w, counts, offsets, bucket_tok, bucket_w);

    // routed gate_up: BM=320 (one m-pass for ne<=320), W streamed once;
    // 1D grid 16 colblk x 64 experts, XCD-swizzled in-kernel
    gu_mfma_kernel<5, true><<<16 * E_NUM, 512, 0, stream>>>(
        xb, Wgu, counts, offsets, bucket_tok, bucket_w, act_r);
    // shared gate_up: BM=128, 16 m-tiles
    gu_mfma_kernel<2, false><<<dim3(16, T_TOK / 128), 512, 0, stream>>>(
        xb, Wsgu, counts, offsets, bucket_tok, bucket_w, act_s);

    // shared down writes out first; routed down accumulates atomically on top
    down_mfma_kernel<2, false><<<dim3(32, T_TOK / 128), 512, 0, stream>>>(
        act_s, Wsd, counts, offsets, bucket_tok, sgate, out);
    down_mfma_kernel<5, true><<<32 * E_NUM, 512, 0, stream>>>(
        act_r, Wd, counts, offsets, bucket_tok, sgate, out);
}

// Round 6
// 810.397 us; speedup vs baseline: 9.4604x; 1.0090x over previous
//
#include <hip/hip_runtime.h>
#include <hip/hip_bf16.h>
#include <math.h>

#define T_TOK 2048
#define H_DIM 2048
#define E_NUM 64
#define F_DIM 512
#define K_TOP 8
#define FS_DIM 512
#define NROWS (T_TOK * K_TOP)

typedef __attribute__((ext_vector_type(8))) short short8v;   // bf16x8 MFMA frag
typedef __attribute__((ext_vector_type(4))) float f32x4;     // MFMA accum

static __device__ __forceinline__ unsigned short f2bf(float f) {
    unsigned int u = __float_as_uint(f);
    u += 0x7fff + ((u >> 16) & 1);           // RNE to bf16
    return (unsigned short)(u >> 16);
}

// bank-conflict-free 16B-chunk swizzle: row stride 64 shorts (128B, bank-neutral),
// chunk = (k8 ^ (row + row/8)) & 7. Write (ushort2) and read (b128) both <=2-way.
#define BCHUNK(row, k8) ((((k8) ^ ((row) + ((row) >> 3)))) & 7)

// raw barrier: LDS writes must be visible (lgkmcnt), but global loads stay in
// flight across the barrier (no vmcnt drain — unlike __syncthreads).
#define PIPE_BARRIER() do { \
    asm volatile("s_waitcnt lgkmcnt(0)" ::: "memory"); \
    __builtin_amdgcn_s_barrier(); \
} while (0)

// ---------------------------------------------------------------------------
// x (fp32) -> bf16 copy, vectorized 8/thread
// ---------------------------------------------------------------------------
__global__ __launch_bounds__(256) void cvt_bf16_kernel(
    const float* __restrict__ in, unsigned short* __restrict__ out, int n8)
{
    int i = blockIdx.x * 256 + threadIdx.x;
    if (i < n8) {
        const float4* p = (const float4*)(in + (size_t)i * 8);
        float4 v0 = p[0], v1 = p[1];
        ushort4 a = make_ushort4(f2bf(v0.x), f2bf(v0.y), f2bf(v0.z), f2bf(v0.w));
        ushort4 b = make_ushort4(f2bf(v1.x), f2bf(v1.y), f2bf(v1.z), f2bf(v1.w));
        ushort4* q = (ushort4*)(out + (size_t)i * 8);
        q[0] = a; q[1] = b;
    }
}

// ---------------------------------------------------------------------------
// Router: one wave per token (fp32 math, exact top-k vs reference).
// ---------------------------------------------------------------------------
__global__ __launch_bounds__(64) void router_kernel(
    const float* __restrict__ x, const float* __restrict__ Wg,
    int* __restrict__ topk_idx, float* __restrict__ topk_w,
    float* __restrict__ sgate, int* __restrict__ counts)
{
    const int t = blockIdx.x;
    const int lane = threadIdx.x;
    const float* xr = x + (size_t)t * H_DIM;

    float a0 = 0.f, a1 = 0.f, a2 = 0.f, a3 = 0.f;
    for (int h = 0; h < H_DIM; h += 4) {
        float4 xv = *(const float4*)&xr[h];
        a0 += xv.x * Wg[(h + 0) * 65 + lane];
        a1 += xv.y * Wg[(h + 1) * 65 + lane];
        a2 += xv.z * Wg[(h + 2) * 65 + lane];
        a3 += xv.w * Wg[(h + 3) * 65 + lane];
    }
    float logit = (a0 + a1) + (a2 + a3);

    float a64 = 0.f;
    for (int h = lane; h < H_DIM; h += 64) a64 += xr[h] * Wg[h * 65 + 64];
#pragma unroll
    for (int off = 32; off >= 1; off >>= 1) a64 += __shfl_xor(a64, off);

    float v = logit;
    float selv[K_TOP]; int seli[K_TOP];
#pragma unroll
    for (int k = 0; k < K_TOP; ++k) {
        float mv = v; int mi = lane;
#pragma unroll
        for (int off = 32; off >= 1; off >>= 1) {
            float ov = __shfl_xor(mv, off);
            int   oi = __shfl_xor(mi, off);
            if (ov > mv || (ov == mv && oi < mi)) { mv = ov; mi = oi; }
        }
        selv[k] = mv; seli[k] = mi;
        if (lane == mi) v = -INFINITY;
    }

    if (lane == 0) {
        float m = selv[0];
        float w[K_TOP]; float s = 0.f;
#pragma unroll
        for (int k = 0; k < K_TOP; ++k) { w[k] = __expf(selv[k] - m); s += w[k]; }
        float inv = 1.f / s;
#pragma unroll
        for (int k = 0; k < K_TOP; ++k) {
            topk_idx[t * K_TOP + k] = seli[k];
            topk_w[t * K_TOP + k] = w[k] * inv;
            atomicAdd(&counts[seli[k]], 1);
        }
        sgate[t] = 1.f / (1.f + __expf(-a64));
    }
}

// ---------------------------------------------------------------------------
// Deterministic per-expert compaction.
// ---------------------------------------------------------------------------
__global__ __launch_bounds__(256) void bucket_kernel(
    const int* __restrict__ topk_idx, const float* __restrict__ topk_w,
    const int* __restrict__ counts, int* __restrict__ offsets,
    int* __restrict__ bucket_tok, float* __restrict__ bucket_w)
{
    const int e = blockIdx.x, thr = threadIdx.x;
    __shared__ int cnt[256];
    __shared__ int base_s;
    const int q0 = thr * 64;
    int c = 0;
    for (int q = 0; q < 64; ++q) c += (topk_idx[q0 + q] == e) ? 1 : 0;
    cnt[thr] = c;
    __syncthreads();
    if (thr == 0) {
        int off = 0;
        for (int i = 0; i < e; ++i) off += counts[i];
        offsets[e] = off;
        base_s = off;
        int run = 0;
        for (int i = 0; i < 256; ++i) { int tval = cnt[i]; cnt[i] = run; run += tval; }
    }
    __syncthreads();
    int pos = base_s + cnt[thr];
    for (int q = 0; q < 64; ++q) {
        int pp = q0 + q;
        if (topk_idx[pp] == e) {
            bucket_tok[pos] = pp >> 3;
            bucket_w[pos] = topk_w[pp];
            ++pos;
        }
    }
}

// ---------------------------------------------------------------------------
// gate_up + SiLU*u*topw. A-frags direct from global bf16; W fp32->bf16
// transposed into LDS (double-buffered, swizzled). Software pipeline with raw
// s_barrier: global loads stay in flight across barriers (no vmcnt drain).
// Per K-step t: ds_write B(t+1); issue W(t+2); load A(t); MFMA buf[t&1]; bar.
// Block 512 thr = 8 waves (4 wm x 2 wn). BM = FM*64, 32 act cols / block.
// ---------------------------------------------------------------------------
template<int FM, bool ROUTED>
__global__ __launch_bounds__(512, 4) void gu_mfma_kernel(
    const unsigned short* __restrict__ xb,
    const float* __restrict__ Wall,
    const int* __restrict__ counts, const int* __restrict__ offsets,
    const int* __restrict__ bucket_tok, const float* __restrict__ bucket_w,
    unsigned short* __restrict__ actout)
{
    constexpr int BM = FM * 64;
    __shared__ __align__(16) unsigned short Bs[2][64 * 64];
    __shared__ int   toksS[BM];
    __shared__ float twsS[BM];

    const int tid  = threadIdx.x;
    const int lane = tid & 63;
    const int wid  = tid >> 6;
    const int wm = wid >> 1, wn = wid & 1;
    const int lrow = lane & 15, lhi = lane >> 4;

    int cblk, ne, base;
    const float* W;
    if (ROUTED) {
        int nw = (blockIdx.x & 7) * ((int)gridDim.x >> 3) + (blockIdx.x >> 3);
        int e = nw >> 4; cblk = nw & 15;
        ne = counts[e]; base = offsets[e];
        W = Wall + (size_t)e * H_DIM * (2 * F_DIM);
    } else {
        cblk = blockIdx.x;
        ne = T_TOK; base = 0;
        W = Wall;
    }
    const int c0 = cblk * 32;               // act-col base

    // W staging geometry: thread covers 4 n-cols x 2 k-rows (float4 x2)
    const int n4 = (tid & 15) * 4;          // Bs n-row base
    const int kb = (tid >> 4) * 2;          // k base (0..62)
    const int n5 = n4 & 31;
    const int wcol = ((n5 < 16) ? 0 : (F_DIM - 16)) + c0 + (n4 >> 5) * 16 + n5;

    // precomputed swizzled LDS write offsets (shorts) for cc=0..3
    int wr_off[4];
#pragma unroll
    for (int cc = 0; cc < 4; ++cc) {
        int n = n4 + cc;
        wr_off[cc] = n * 64 + BCHUNK(n, kb >> 3) * 8 + (kb & 7);
    }
    // swizzled read offsets for the two frag rows (per ks in {0,1} -> kc=ks*4+lhi)
    const int rg = wn * 32 + lrow, ru = wn * 32 + 16 + lrow;
    int rd_g[2], rd_u[2];
#pragma unroll
    for (int ks = 0; ks < 2; ++ks) {
        int kc = ks * 4 + lhi;
        rd_g[ks] = rg * 64 + BCHUNK(rg, kc) * 8;
        rd_u[ks] = ru * 64 + BCHUNK(ru, kc) * 8;
    }

    const int m0_beg = ROUTED ? 0 : blockIdx.y * BM;
    const int m0_end = ROUTED ? ne : m0_beg + BM;

    for (int m0 = m0_beg; m0 < m0_end; m0 += BM) {
        __syncthreads();
        for (int i = tid; i < BM; i += 512) {
            if (ROUTED) {
                int idx = m0 + i; bool v = idx < ne;
                toksS[i] = v ? bucket_tok[base + idx] : bucket_tok[base];
                twsS[i]  = v ? bucket_w[base + idx] : 0.f;
            } else {
                toksS[i] = m0 + i; twsS[i] = 1.f;
            }
        }
        __syncthreads();

        const unsigned short* aptr[FM];
#pragma unroll
        for (int fm = 0; fm < FM; ++fm) {
            int r = wm * (FM * 16) + fm * 16 + lrow;
            aptr[fm] = xb + (size_t)toksS[r] * H_DIM;
        }

        f32x4 acc[FM][2];
#pragma unroll
        for (int i = 0; i < FM; ++i) {
            acc[i][0] = (f32x4){0.f, 0.f, 0.f, 0.f};
            acc[i][1] = (f32x4){0.f, 0.f, 0.f, 0.f};
        }

        const int NT = H_DIM / 64;
        // prologue: W(0) -> LDS buf0; issue W(1)
        float4 b0 = *(const float4*)&W[(size_t)kb * (2 * F_DIM) + wcol];
        float4 b1 = *(const float4*)&W[(size_t)(kb + 1) * (2 * F_DIM) + wcol];
#pragma unroll
        for (int cc = 0; cc < 4; ++cc)
            *(ushort2*)&Bs[0][wr_off[cc]] = make_ushort2(
                f2bf(((const float*)&b0)[cc]), f2bf(((const float*)&b1)[cc]));
        b0 = *(const float4*)&W[(size_t)(64 + kb) * (2 * F_DIM) + wcol];
        b1 = *(const float4*)&W[(size_t)(64 + kb + 1) * (2 * F_DIM) + wcol];
        PIPE_BARRIER();

        for (int kt = 0; kt < NT - 1; ++kt) {
            const int k0 = kt * 64;
            // write B(kt+1) into the other buffer (waits only on b0/b1 regs)
            unsigned short* nxtB = Bs[(kt & 1) ^ 1];
#pragma unroll
            for (int cc = 0; cc < 4; ++cc)
                *(ushort2*)&nxtB[wr_off[cc]] = make_ushort2(
                    f2bf(((const float*)&b0)[cc]), f2bf(((const float*)&b1)[cc]));
            // issue W(kt+2) — stays in flight across the barrier
            if (kt < NT - 2) {
                b0 = *(const float4*)&W[(size_t)(k0 + 128 + kb) * (2 * F_DIM) + wcol];
                b1 = *(const float4*)&W[(size_t)(k0 + 128 + kb + 1) * (2 * F_DIM) + wcol];
            }
            // A frags for this step + MFMA on current buffer
            const unsigned short* curB = Bs[kt & 1];
#pragma unroll
            for (int ks = 0; ks < 2; ++ks) {
                short8v bg = *(const short8v*)&curB[rd_g[ks]];
                short8v bu = *(const short8v*)&curB[rd_u[ks]];
                const int koff = k0 + (ks * 4 + lhi) * 8;
#pragma unroll
                for (int fm = 0; fm < FM; ++fm) {
                    short8v af = *(const short8v*)(aptr[fm] + koff);
                    acc[fm][0] = __builtin_amdgcn_mfma_f32_16x16x32_bf16(af, bg, acc[fm][0], 0, 0, 0);
                    acc[fm][1] = __builtin_amdgcn_mfma_f32_16x16x32_bf16(af, bu, acc[fm][1], 0, 0, 0);
                }
            }
            PIPE_BARRIER();
        }
        // final step: MFMA only
        {
            const int k0 = (NT - 1) * 64;
            const unsigned short* curB = Bs[(NT - 1) & 1];
#pragma unroll
            for (int ks = 0; ks < 2; ++ks) {
                short8v bg = *(const short8v*)&curB[rd_g[ks]];
                short8v bu = *(const short8v*)&curB[rd_u[ks]];
                const int koff = k0 + (ks * 4 + lhi) * 8;
#pragma unroll
                for (int fm = 0; fm < FM; ++fm) {
                    short8v af = *(const short8v*)(aptr[fm] + koff);
                    acc[fm][0] = __builtin_amdgcn_mfma_f32_16x16x32_bf16(af, bg, acc[fm][0], 0, 0, 0);
                    acc[fm][1] = __builtin_amdgcn_mfma_f32_16x16x32_bf16(af, bu, acc[fm][1], 0, 0, 0);
                }
            }
        }

        // epilogue: silu(g)*u*topw -> bf16 act
        const int acol = c0 + wn * 16 + lrow;
#pragma unroll
        for (int fm = 0; fm < FM; ++fm) {
#pragma unroll
            for (int i = 0; i < 4; ++i) {
                int ml = wm * (FM * 16) + fm * 16 + lhi * 4 + i;
                int idx = m0 + ml;
                if (!ROUTED || idx < ne) {
                    float gv = acc[fm][0][i], uv = acc[fm][1][i];
                    float s = gv / (1.f + __expf(-gv));
                    float val = s * uv * twsS[ml];
                    size_t orow = ROUTED ? (size_t)(base + idx) : (size_t)idx;
                    actout[orow * F_DIM + acol] = f2bf(val);
                }
            }
        }
    }
}

// ---------------------------------------------------------------------------
// down-proj, same pipelined structure. ROUTED: atomicAdd; shared: store*sig.
// ---------------------------------------------------------------------------
template<int FM, bool ROUTED>
__global__ __launch_bounds__(512, 4) void down_mfma_kernel(
    const unsigned short* __restrict__ actb,
    const float* __restrict__ Wall,
    const int* __restrict__ counts, const int* __restrict__ offsets,
    const int* __restrict__ bucket_tok, const float* __restrict__ sgate,
    float* __restrict__ out)
{
    constexpr int BM = FM * 64;
    __shared__ __align__(16) unsigned short Bs[2][64 * 64];
    __shared__ int   toksS[BM];
    __shared__ float sgS[BM];

    const int tid  = threadIdx.x;
    const int lane = tid & 63;
    const int wid  = tid >> 6;
    const int wm = wid >> 1, wn = wid & 1;
    const int lrow = lane & 15, lhi = lane >> 4;

    int cblk, ne, base;
    const float* W;
    if (ROUTED) {
        int nw = (blockIdx.x & 7) * ((int)gridDim.x >> 3) + (blockIdx.x >> 3);
        int e = nw >> 5; cblk = nw & 31;
        ne = counts[e]; base = offsets[e];
        W = Wall + (size_t)e * F_DIM * H_DIM;
    } else {
        cblk = blockIdx.x;
        ne = T_TOK; base = 0;
        W = Wall;
    }
    const int c0 = cblk * 64;

    const int n4 = (tid & 15) * 4;
    const int kb = (tid >> 4) * 2;
    const int wcol = c0 + n4;

    int wr_off[4];
#pragma unroll
    for (int cc = 0; cc < 4; ++cc) {
        int n = n4 + cc;
        wr_off[cc] = n * 64 + BCHUNK(n, kb >> 3) * 8 + (kb & 7);
    }
    const int r0 = wn * 32 + lrow, r1 = wn * 32 + 16 + lrow;
    int rd_0[2], rd_1[2];
#pragma unroll
    for (int ks = 0; ks < 2; ++ks) {
        int kc = ks * 4 + lhi;
        rd_0[ks] = r0 * 64 + BCHUNK(r0, kc) * 8;
        rd_1[ks] = r1 * 64 + BCHUNK(r1, kc) * 8;
    }

    const int m0_beg = ROUTED ? 0 : blockIdx.y * BM;
    const int m0_end = ROUTED ? ne : m0_beg + BM;

    for (int m0 = m0_beg; m0 < m0_end; m0 += BM) {
        __syncthreads();
        for (int i = tid; i < BM; i += 512) {
            if (ROUTED) {
                int idx = m0 + i;
                toksS[i] = (idx < ne) ? bucket_tok[base + idx] : 0;
            } else {
                sgS[i] = sgate[m0 + i];
            }
        }
        __syncthreads();

        const unsigned short* aptr[FM];
#pragma unroll
        for (int fm = 0; fm < FM; ++fm) {
            int r = wm * (FM * 16) + fm * 16 + lrow;
            int grow = ROUTED ? min(base + m0 + r, NROWS - 1) : (m0 + r);
            aptr[fm] = actb + (size_t)grow * F_DIM;
        }

        f32x4 acc[FM][2];
#pragma unroll
        for (int i = 0; i < FM; ++i) {
            acc[i][0] = (f32x4){0.f, 0.f, 0.f, 0.f};
            acc[i][1] = (f32x4){0.f, 0.f, 0.f, 0.f};
        }

        const int NT = F_DIM / 64;
        float4 b0 = *(const float4*)&W[(size_t)kb * H_DIM + wcol];
        float4 b1 = *(const float4*)&W[(size_t)(kb + 1) * H_DIM + wcol];
#pragma unroll
        for (int cc = 0; cc < 4; ++cc)
            *(ushort2*)&Bs[0][wr_off[cc]] = make_ushort2(
                f2bf(((const float*)&b0)[cc]), f2bf(((const float*)&b1)[cc]));
        b0 = *(const float4*)&W[(size_t)(64 + kb) * H_DIM + wcol];
        b1 = *(const float4*)&W[(size_t)(64 + kb + 1) * H_DIM + wcol];
        PIPE_BARRIER();

        for (int kt = 0; kt < NT - 1; ++kt) {
            const int k0 = kt * 64;
            unsigned short* nxtB = Bs[(kt & 1) ^ 1];
#pragma unroll
            for (int cc = 0; cc < 4; ++cc)
                *(ushort2*)&nxtB[wr_off[cc]] = make_ushort2(
                    f2bf(((const float*)&b0)[cc]), f2bf(((const float*)&b1)[cc]));
            if (kt < NT - 2) {
                b0 = *(const float4*)&W[(size_t)(k0 + 128 + kb) * H_DIM + wcol];
                b1 = *(const float4*)&W[(size_t)(k0 + 128 + kb + 1) * H_DIM + wcol];
            }
            const unsigned short* curB = Bs[kt & 1];
#pragma unroll
            for (int ks = 0; ks < 2; ++ks) {
                short8v bf0 = *(const short8v*)&curB[rd_0[ks]];
                short8v bf1 = *(const short8v*)&curB[rd_1[ks]];
                const int koff = k0 + (ks * 4 + lhi) * 8;
#pragma unroll
                for (int fm = 0; fm < FM; ++fm) {
                    short8v af = *(const short8v*)(aptr[fm] + koff);
                    acc[fm][0] = __builtin_amdgcn_mfma_f32_16x16x32_bf16(af, bf0, acc[fm][0], 0, 0, 0);
                    acc[fm][1] = __builtin_amdgcn_mfma_f32_16x16x32_bf16(af, bf1, acc[fm][1], 0, 0, 0);
                }
            }
            PIPE_BARRIER();
        }
        {
            const int k0 = (NT - 1) * 64;
            const unsigned short* curB = Bs[(NT - 1) & 1];
#pragma unroll
            for (int ks = 0; ks < 2; ++ks) {
                short8v bf0 = *(const short8v*)&curB[rd_0[ks]];
                short8v bf1 = *(const short8v*)&curB[rd_1[ks]];
                const int koff = k0 + (ks * 4 + lhi) * 8;
#pragma unroll
                for (int fm = 0; fm < FM; ++fm) {
                    short8v af = *(const short8v*)(aptr[fm] + koff);
                    acc[fm][0] = __builtin_amdgcn_mfma_f32_16x16x32_bf16(af, bf0, acc[fm][0], 0, 0, 0);
                    acc[fm][1] = __builtin_amdgcn_mfma_f32_16x16x32_bf16(af, bf1, acc[fm][1], 0, 0, 0);
                }
            }
        }

#pragma unroll
        for (int fm = 0; fm < FM; ++fm) {
#pragma unroll
            for (int fn = 0; fn < 2; ++fn) {
                int col = c0 + wn * 32 + fn * 16 + lrow;
#pragma unroll
                for (int i = 0; i < 4; ++i) {
                    int ml = wm * (FM * 16) + fm * 16 + lhi * 4 + i;
                    int idx = m0 + ml;
                    if (ROUTED) {
                        if (idx < ne)
                            atomicAdd(&out[(size_t)toksS[ml] * H_DIM + col], acc[fm][fn][i]);
                    } else {
                        out[(size_t)idx * H_DIM + col] = sgS[ml] * acc[fm][fn][i];
                    }
                }
            }
        }
    }
}

// ---------------------------------------------------------------------------
extern "C" void kernel_launch(void* const* d_in, const int* in_sizes, int n_in,
                              void* d_out, int out_size, void* d_ws, size_t ws_size,
                              hipStream_t stream) {
    const float* x    = (const float*)d_in[0];
    const float* Wg   = (const float*)d_in[1];
    const float* Wgu  = (const float*)d_in[2];
    const float* Wd   = (const float*)d_in[3];
    const float* Wsgu = (const float*)d_in[4];
    const float* Wsd  = (const float*)d_in[5];
    float* out = (float*)d_out;

    char* p = (char*)d_ws;
    auto alloc = [&](size_t bytes) {
        char* r = p;
        p += (bytes + 255) & ~(size_t)255;
        return r;
    };
    int*   topk_idx   = (int*)  alloc((size_t)T_TOK * K_TOP * sizeof(int));
    float* topk_w     = (float*)alloc((size_t)T_TOK * K_TOP * sizeof(float));
    float* sgate      = (float*)alloc((size_t)T_TOK * sizeof(float));
    int*   counts     = (int*)  alloc((size_t)E_NUM * sizeof(int));
    int*   offsets    = (int*)  alloc((size_t)E_NUM * sizeof(int));
    int*   bucket_tok = (int*)  alloc((size_t)NROWS * sizeof(int));
    float* bucket_w   = (float*)alloc((size_t)NROWS * sizeof(float));
    unsigned short* xb    = (unsigned short*)alloc((size_t)T_TOK * H_DIM * sizeof(short));
    unsigned short* act_r = (unsigned short*)alloc((size_t)NROWS * F_DIM * sizeof(short));
    unsigned short* act_s = (unsigned short*)alloc((size_t)T_TOK * FS_DIM * sizeof(short));

    hipMemsetAsync(counts, 0, E_NUM * sizeof(int), stream);
    cvt_bf16_kernel<<<(T_TOK * H_DIM / 8 + 255) / 256, 256, 0, stream>>>(x, xb, T_TOK * H_DIM / 8);
    router_kernel<<<T_TOK, 64, 0, stream>>>(x, Wg, topk_idx, topk_w, sgate, counts);
    bucket_kernel<<<E_NUM, 256, 0, stream>>>(topk_idx, topk_w, counts, offsets, bucket_tok, bucket_w);

    // routed gate_up: BM=320 (one m-pass for ne<=320), W streamed once;
    // 1D grid 16 colblk x 64 experts, XCD-swizzled in-kernel
    gu_mfma_kernel<5, true><<<16 * E_NUM, 512, 0, stream>>>(
        xb, Wgu, counts, offsets, bucket_tok, bucket_w, act_r);
    // shared gate_up: BM=128, 16 m-tiles
    gu_mfma_kernel<2, false><<<dim3(16, T_TOK / 128), 512, 0, stream>>>(
        xb, Wsgu, counts, offsets, bucket_tok, bucket_w, act_s);

    // shared down writes out first; routed down accumulates atomically on top
    down_mfma_kernel<2, false><<<dim3(32, T_TOK / 128), 512, 0, stream>>>(
        act_s, Wsd, counts, offsets, bucket_tok, sgate, out);
    down_mfma_kernel<5, true><<<32 * E_NUM, 512, 0, stream>>>(
        act_r, Wd, counts, offsets, bucket_tok, sgate, out);
}